// Round 20
// baseline (207.143 us; speedup 1.0000x reference)
//
#include <hip/hip_runtime.h>

#define F_ 8
#define C_ 128
#define C2_ (C_/2)   // 64 c-pairs
#define H_ 96
#define W_ 96
#define P_ (H_*W_)   // 9216
#define I_ 64
#define I2_ (I_/2)   // 32 i-pairs
#define T_ 17
#define KK_ (F_*T_)  // 136

// compile-time tap offsets (full unroll -> immediates) — used by k_scores / k_yr
__device__ constexpr int DY[T_] = {-1,-1,-1, 0,0,0, 1,1,1, -3,-3,-3, 0,0, 3,3,3};
__device__ constexpr int DX[T_] = {-1, 0, 1,-1,0,1,-1,0,1, -3, 0, 3,-3,3,-3,0,3};

// dy-grouped tap order for k_y (consecutive taps share cache lines; CK = original k)
__constant__ int CDY[T_] = {-3,-3,-3, -1,-1,-1,  0, 0,0,0, 0,  1,1,1,  3, 3, 3};
__constant__ int CDX[T_] = {-3, 0, 3, -1, 0, 1, -3,-1,0,1, 3, -1,0,1, -3, 0, 3};
__constant__ int CK [T_] = { 9,10,11,  0, 1, 2, 12, 3,4,5,13,  6,7,8, 14,15,16};

typedef unsigned short u16;
typedef u16 u16x8 __attribute__((ext_vector_type(8)));
typedef float f32x2 __attribute__((ext_vector_type(2)));
typedef float f32x4 __attribute__((ext_vector_type(4)));
typedef _Float16 h16x2 __attribute__((ext_vector_type(2)));
typedef _Float16 h16x8 __attribute__((ext_vector_type(8)));

__device__ __forceinline__ float b2f(u16 u) { return __uint_as_float(((unsigned)u) << 16); }
__device__ __forceinline__ float pairLo(unsigned v) { return __uint_as_float(v << 16); }
__device__ __forceinline__ float pairHi(unsigned v) { return __uint_as_float(v & 0xffff0000u); }
__device__ __forceinline__ u16 f2b(float f) {
    unsigned u = __float_as_uint(f);
    u += 0x7fff + ((u >> 16) & 1);   // RNE
    return (u16)(u >> 16);
}
__device__ __forceinline__ h16x2 u2h(unsigned u) {
    union { unsigned u; h16x2 h; } x; x.u = u; return x.h;
}
__device__ __forceinline__ unsigned packh(float a, float b) {
    union { unsigned u; h16x2 h; } x;
    x.h[0] = (_Float16)a; x.h[1] = (_Float16)b; return x.u;
}
__device__ __forceinline__ float dot2(h16x2 a, h16x2 b, float c) {
#if __has_builtin(__builtin_amdgcn_fdot2)
    return __builtin_amdgcn_fdot2(a, b, c, false);
#else
    return c + (float)a[0] * (float)b[0] + (float)a[1] * (float)b[1];
#endif
}

// vt[c], u[c] fp32; uh = fp16-pair-packed u; ct[0]=wt.rtb; ct[1]=wp.rpb
__global__ __launch_bounds__(128) void k_prep(const float* __restrict__ rtw,
                                              const float* __restrict__ rpw,
                                              const float* __restrict__ rtb,
                                              const float* __restrict__ rpb,
                                              const float* __restrict__ cp,
                                              float* __restrict__ vt,
                                              float* __restrict__ u,
                                              float* __restrict__ ct,
                                              unsigned* __restrict__ uh) {
    __shared__ float su[C_];
    int c = threadIdx.x;  // 128
    float a = 0.f, b2 = 0.f;
    for (int i = 0; i < I_; ++i) {
        a  += cp[i]      * rtw[i*C_ + c];
        b2 += cp[I_ + i] * rpw[i*C_ + c];
    }
    vt[c] = a; u[c] = b2; su[c] = b2;
    if (c == 0) { float s = 0.f; for (int i = 0; i < I_; ++i) s += cp[i]      * rtb[i]; ct[0] = s; }
    if (c == 1) { float s = 0.f; for (int i = 0; i < I_; ++i) s += cp[I_ + i] * rpb[i]; ct[1] = s; }
    __syncthreads();
    if (c < C2_) uh[c] = packh(su[2*c], su[2*c+1]);
}

// weight prep (rg/W/rW paths): 0: rg fp32 [C][I]; 1-2: W/rW fp32 [I][C]
__global__ __launch_bounds__(256) void k_tr(const float* __restrict__ rg_w,
                                            const float* __restrict__ W_w,
                                            const float* __restrict__ rW_w,
                                            float* __restrict__ rgT,
                                            float* __restrict__ WT,
                                            float* __restrict__ rWT) {
    int which = blockIdx.y;
    int idx = blockIdx.x * 256 + threadIdx.x;
    if (which == 0) {
        int r = idx / C_, c = idx % C_;
        rgT[c*I_ + r] = rg_w[idx];
    } else {
        const float* src = which == 1 ? W_w : rW_w;
        float*       dst = which == 1 ? WT  : rWT;
        int r = idx / I_, c = idx % I_;
        dst[c*C_ + r] = src[idx];
    }
}

// MFMA weight prepack: Wpk fragment-linear (13 n-tiles x 4 k-steps x 64 lanes x 8 halfs).
// n<192: proj weights; n==192: u[c] (Bf row); bias table ball[208].
__global__ __launch_bounds__(256) void k_wpk(const float* __restrict__ g_w,
                                             const float* __restrict__ th_w,
                                             const float* __restrict__ ph_w,
                                             const float* __restrict__ g_b,
                                             const float* __restrict__ th_b,
                                             const float* __restrict__ ph_b,
                                             const float* __restrict__ u,
                                             const float* __restrict__ ct,
                                             _Float16* __restrict__ Wpk,
                                             float* __restrict__ ball) {
    int idx = blockIdx.x * 256 + threadIdx.x;   // over 13*4*64*8 = 26624
    if (idx < 26624) {
        int j    = idx & 7;
        int frag = idx >> 3;
        int l    = frag & 63;
        int t    = frag >> 6;      // nt*4 + ks
        int ks   = t & 3;
        int nt   = t >> 2;
        int c = ks * 32 + ((l >> 4) << 3) + j;
        int n = nt * 16 + (l & 15);
        float v;
        if (n < 192) {
            int proj = n >> 6, i = n & 63;
            const float* src = proj == 0 ? g_w : (proj == 1 ? th_w : ph_w);
            v = src[i * C_ + c];
        } else if (n == 192) v = u[c];
        else v = 0.f;
        Wpk[idx] = (_Float16)v;
    }
    if (idx < 208) {
        float b;
        if (idx < 192) {
            int proj = idx >> 6, i = idx & 63;
            const float* bs = proj == 0 ? g_b : (proj == 1 ? th_b : ph_b);
            b = bs[i];
        } else if (idx == 192) b = ct[1];
        else b = 0.f;
        ball[idx] = b;
    }
}

// x fp32 [f][c][p] -> fp16 row-major xhT[f][p][c] (c contiguous, MFMA-fragment friendly)
__global__ __launch_bounds__(256) void k_xhT(const float* __restrict__ x,
                                             _Float16* __restrict__ xhT) {
    int p  = blockIdx.x * 256 + threadIdx.x;
    int cb = blockIdx.y;        // 4 blocks of 32 c
    int f  = blockIdx.z;
    const float* xp = x + ((size_t)f * C_ + cb * 32) * P_ + p;
    unsigned r[16];
#pragma unroll
    for (int jj = 0; jj < 16; ++jj) {
        float a = xp[(size_t)(2 * jj)     * P_];
        float b = xp[(size_t)(2 * jj + 1) * P_];
        r[jj] = packh(a, b);
    }
    unsigned* dst = (unsigned*)(xhT + ((size_t)f * P_ + p) * C_ + cb * 32);
#pragma unroll
    for (int q4 = 0; q4 < 4; ++q4) {
        uint4 v; v.x = r[q4*4]; v.y = r[q4*4+1]; v.z = r[q4*4+2]; v.w = r[q4*4+3];
        *(uint4*)(dst + q4 * 4) = v;
    }
}

// MFMA projections: per f, D[n=0..207][px] = W^T x. 16x16x32 f16, fp32 accum.
__global__ __launch_bounds__(256) void k_projm(const _Float16* __restrict__ xhT,
                                               const h16x8* __restrict__ Wpk,
                                               const float* __restrict__ ball,
                                               unsigned* __restrict__ oG,
                                               unsigned* __restrict__ oT,
                                               unsigned* __restrict__ oP,
                                               float* __restrict__ Bf) {
    int wid  = threadIdx.x >> 6;
    int lane = threadIdx.x & 63;
    int px0  = blockIdx.x * 64 + wid * 16;
    int f    = blockIdx.z;
    int lm   = lane & 15;
    int lg   = lane >> 4;
    const _Float16* xrow = xhT + ((size_t)f * P_ + px0 + lm) * C_ + lg * 8;
    h16x8 bfrag[4];
#pragma unroll
    for (int ks = 0; ks < 4; ++ks)
        bfrag[ks] = *(const h16x8*)(xrow + ks * 32);
#pragma unroll 1
    for (int nt = 0; nt < 13; ++nt) {
        f32x4 acc = {0.f, 0.f, 0.f, 0.f};
#pragma unroll
        for (int ks = 0; ks < 4; ++ks) {
            h16x8 afrag = Wpk[(nt * 4 + ks) * 64 + lane];
            acc = __builtin_amdgcn_mfma_f32_16x16x32_f16(afrag, bfrag[ks], acc, 0, 0, 0);
        }
        int nb = nt * 16 + lg * 4;     // 4 consecutive n in regs 0..3
        if (nb < 192) {
            int proj = nb >> 6, i = nb & 63, i2 = i >> 1;
            unsigned* o = proj == 0 ? oG : (proj == 1 ? oT : oP);
            size_t base = ((size_t)f * I2_ + i2) * P_ + px0 + lm;
            o[base]      = packh(acc[0] + ball[nb],     acc[1] + ball[nb + 1]);
            o[base + P_] = packh(acc[2] + ball[nb + 2], acc[3] + ball[nb + 3]);
        } else if (nb == 192) {
            Bf[(size_t)f * P_ + px0 + lm] = acc[0] + ball[192];
        }
    }
}

// y<4: GR[i0..i0+16)[p] fp32 = conv(rgb, rgT) + rg_b;  y==4: SR[p] = ct0 + rgb.vt
__global__ __launch_bounds__(256) void k_rg(const float* __restrict__ rgb,
                                            const float* __restrict__ rgT,
                                            const float* __restrict__ rg_b,
                                            const float* __restrict__ vt,
                                            const float* __restrict__ ct,
                                            float* __restrict__ GR,
                                            float* __restrict__ SR) {
    int p = blockIdx.x * 256 + threadIdx.x;
    int y = blockIdx.y;
    if (y == 4) {
        float s = ct[0];
        for (int c = 0; c < C_; ++c) s += rgb[(size_t)c * P_ + p] * vt[c];
        SR[p] = s;
        return;
    }
    int i0 = y * 16;
    float acc[16];
#pragma unroll
    for (int ii = 0; ii < 16; ++ii) acc[ii] = 0.f;
#pragma unroll 2
    for (int c = 0; c < C_; ++c) {
        float xv = rgb[(size_t)c * P_ + p];
        const float* wr = rgT + (size_t)c * I_ + i0;
#pragma unroll
        for (int ii = 0; ii < 16; ++ii) acc[ii] += xv * wr[ii];
    }
#pragma unroll
    for (int ii = 0; ii < 16; ++ii) GR[(size_t)(i0 + ii) * P_ + p] = acc[ii] + rg_b[i0 + ii];
}

// scores: S[k][p][f1] (bf16) = exp(mask * sum_i PH.TH); k-block 2 for 2x occupancy
__global__ __launch_bounds__(256) void k_scores(const unsigned* __restrict__ PHu,
                                                const unsigned* __restrict__ THu,
                                                u16* __restrict__ S) {
    int p  = blockIdx.x * 256 + threadIdx.x;
    int k0 = blockIdx.y * 2;
    int px = p % W_, py = p / W_;
    size_t tb[2]; float msk[2];
#pragma unroll
    for (int kk = 0; kk < 2; ++kk) {
        int k  = k0 + kk;
        int f2 = k / T_;
        int t  = k - f2 * T_;
        int dy = DY[t], dx = DX[t];
        bool v = ((unsigned)(py + dy) < H_) && ((unsigned)(px + dx) < W_);
        int q  = p + dy * W_ + dx;
        q = min(max(q, 0), P_ - 1);
        tb[kk]  = (size_t)f2 * I2_ * P_ + q;
        msk[kk] = v ? 1.f : 0.f;
    }
    float acc[8][2];
#pragma unroll
    for (int a = 0; a < 8; ++a)
#pragma unroll
        for (int b = 0; b < 2; ++b) acc[a][b] = 0.f;
#pragma unroll 2
    for (int i2 = 0; i2 < I2_; ++i2) {
        h16x2 ph[8];
#pragma unroll
        for (int f1 = 0; f1 < 8; ++f1)
            ph[f1] = u2h(PHu[((size_t)f1 * I2_ + i2) * P_ + p]);
        h16x2 tv[2];
#pragma unroll
        for (int kk = 0; kk < 2; ++kk)
            tv[kk] = u2h(THu[tb[kk] + (size_t)i2 * P_]);
#pragma unroll
        for (int kk = 0; kk < 2; ++kk)
#pragma unroll
            for (int f1 = 0; f1 < 8; ++f1)
                acc[f1][kk] = dot2(ph[f1], tv[kk], acc[f1][kk]);
    }
    // exp folded (|score| << 88); OOB -> exp(0)=1, matches reference denominator
#pragma unroll
    for (int kk = 0; kk < 2; ++kk) {
        u16x8 r;
#pragma unroll
        for (int f1 = 0; f1 < 8; ++f1) r[f1] = f2b(__expf(acc[f1][kk] * msk[kk]));
        *(u16x8*)(S + ((size_t)(k0 + kk) * P_ + p) * 8) = r;
    }
}

// k_y: f1-split x2 + f2-quarter split. thread = 1px x 4f1 x 8i.
// grid (P/256, 8, 8): z = qtr*2 + f1half -> 9216 waves (9/SIMD).
// S read: aligned uint2 (4 f1). Yp[qtr][f][ib][p][8i] bf16; den by iblk==0.
__global__ __launch_bounds__(256) void k_y(const u16* __restrict__ S,
                                           const u16* __restrict__ G,
                                           u16* __restrict__ Yp,
                                           float* __restrict__ DEN) {
    int p   = blockIdx.x * 256 + threadIdx.x;
    int ib  = blockIdx.y;           // i-block: i = ib*8 + ii
    int z   = blockIdx.z;
    int qtr = z >> 1;
    int f10 = (z & 1) * 4;
    int px = p % W_, py = p / W_;
    const unsigned* Gu = (const unsigned*)G;
    f32x2 acc2[4][4];
    float den[4];
#pragma unroll
    for (int a = 0; a < 4; ++a) {
        den[a] = 0.f;
#pragma unroll
        for (int b = 0; b < 4; ++b) acc2[a][b] = 0.f;
    }
#pragma unroll 1
    for (int f2 = qtr * 2; f2 < qtr * 2 + 2; ++f2) {
        const unsigned* Gb = Gu + ((size_t)f2 * I2_ + ib * 4) * P_;
#pragma unroll 1
        for (int t = 0; t < T_; ++t) {
            int dy = CDY[t], dx = CDX[t], k = CK[t];
            bool v = ((unsigned)(py + dy) < H_) && ((unsigned)(px + dx) < W_);
            int q  = p + dy * W_ + dx;
            q = min(max(q, 0), P_ - 1);
            float mt = v ? 1.f : 0.f;
            f32x2 mt2; mt2[0] = mt; mt2[1] = mt;
            uint2 sw = *(const uint2*)(S + ((size_t)(f2 * T_ + k) * P_ + p) * 8 + f10);
            float sv[4];
            sv[0] = pairLo(sw.x); sv[1] = pairHi(sw.x);
            sv[2] = pairLo(sw.y); sv[3] = pairHi(sw.y);
            f32x2 gv2[4];
#pragma unroll
            for (int jj = 0; jj < 4; ++jj) {
                h16x2 h = u2h(Gb[(size_t)jj * P_ + q]);
                f32x2 g; g[0] = (float)h[0]; g[1] = (float)h[1];
                gv2[jj] = g * mt2;           // v_pk_mul_f32
            }
#pragma unroll
            for (int ff = 0; ff < 4; ++ff) {
                den[ff] += sv[ff];
                f32x2 s2; s2[0] = sv[ff]; s2[1] = sv[ff];
#pragma unroll
                for (int jj = 0; jj < 4; ++jj)
                    acc2[ff][jj] += s2 * gv2[jj];   // v_pk_fma_f32
            }
        }
    }
    if (blockIdx.y == 0) {
#pragma unroll
        for (int ff = 0; ff < 4; ++ff)
            DEN[(size_t)(qtr * F_ + f10 + ff) * P_ + p] = den[ff];
    }
    u16* Yh = Yp + (size_t)qtr * F_ * P_ * I_;
#pragma unroll
    for (int ff = 0; ff < 4; ++ff) {
        u16x8 r;
#pragma unroll
        for (int ii = 0; ii < 8; ++ii) r[ii] = f2b(acc2[ff][ii >> 1][ii & 1]);
        *(u16x8*)(Yh + (((size_t)(f10 + ff) * 8 + ib) * P_ + p) * 8) = r;
    }
}

// Yr[f][ib][p][8i] bf16 = sum_t relu(SR[q]+Bf[f][p])/T * GR[i][q]; pk-FMA over ii-pairs
__global__ __launch_bounds__(128) void k_yr(const float* __restrict__ SR,
                                            const float* __restrict__ Bf,
                                            const float* __restrict__ GR,
                                            u16* __restrict__ Yr) {
    int p  = blockIdx.x * 128 + threadIdx.x;
    int ib = blockIdx.y;
    int i0 = ib * 8;
    int px = p % W_, py = p / W_;
    float bfv[8];
#pragma unroll
    for (int f = 0; f < 8; ++f) bfv[f] = Bf[f * P_ + p];
    f32x2 acc2[8][4];
#pragma unroll
    for (int a = 0; a < 8; ++a)
#pragma unroll
        for (int b = 0; b < 4; ++b) acc2[a][b] = 0.f;
#pragma unroll
    for (int t = 0; t < T_; ++t) {
        int dy = DY[t], dx = DX[t];
        bool v = ((unsigned)(py + dy) < H_) && ((unsigned)(px + dx) < W_);
        int q  = p + dy * W_ + dx;
        q = min(max(q, 0), P_ - 1);
        float sr = SR[q];
        f32x2 gr2[4];
#pragma unroll
        for (int jj = 0; jj < 4; ++jj) {
            f32x2 g;
            g[0] = GR[(size_t)(i0 + 2*jj)     * P_ + q];
            g[1] = GR[(size_t)(i0 + 2*jj + 1) * P_ + q];
            gr2[jj] = g;
        }
#pragma unroll
        for (int f = 0; f < 8; ++f) {
            float fv = v ? fmaxf(sr + bfv[f], 0.f) * (1.f / (float)T_) : 0.f;
            f32x2 f2v; f2v[0] = fv; f2v[1] = fv;
#pragma unroll
            for (int jj = 0; jj < 4; ++jj) acc2[f][jj] += f2v * gr2[jj];
        }
    }
#pragma unroll
    for (int f = 0; f < 8; ++f) {
        u16x8 r;
#pragma unroll
        for (int ii = 0; ii < 8; ++ii) r[ii] = f2b(acc2[f][ii >> 1][ii & 1]);
        *(u16x8*)(Yr + (((size_t)f * 8 + ib) * P_ + p) * 8) = r;
    }
}

// k_fold: Ysum[f][i8][p][8] bf16 = (sum_q Ypq) * dv
__global__ __launch_bounds__(256) void k_fold(const u16* __restrict__ Yp,
                                              const float* __restrict__ DEN,
                                              u16* __restrict__ Ys) {
    int p  = blockIdx.x * 256 + threadIdx.x;
    int i8 = blockIdx.y;
    int f  = blockIdx.z;
    float dv = 1.f / (DEN[(size_t)f * P_ + p]
                    + DEN[(size_t)(F_ + f) * P_ + p]
                    + DEN[(size_t)(2 * F_ + f) * P_ + p]
                    + DEN[(size_t)(3 * F_ + f) * P_ + p]);
    const size_t FPI = (size_t)F_ * P_ * I_;
    size_t base = (((size_t)f * 8 + i8) * P_ + p) * 8;
    u16x8 q0 = *(const u16x8*)(Yp + base);
    u16x8 q1 = *(const u16x8*)(Yp + FPI + base);
    u16x8 q2 = *(const u16x8*)(Yp + 2 * FPI + base);
    u16x8 q3 = *(const u16x8*)(Yp + 3 * FPI + base);
    u16x8 r;
#pragma unroll
    for (int j = 0; j < 8; ++j)
        r[j] = f2b((b2f(q0[j]) + b2f(q1[j]) + b2f(q2[j]) + b2f(q3[j])) * dv);
    *(u16x8*)(Ys + base) = r;
}

// out[f][c][p] = sum_i Ysum_i*WT[i][c] + sum_i Yr_i*rWT[i][c] + Wb + rWb + x
__global__ __launch_bounds__(256) void k_final(const u16* __restrict__ Ys,
                                               const u16* __restrict__ Yr,
                                               const float* __restrict__ WT,
                                               const float* __restrict__ rWT,
                                               const float* __restrict__ Wb,
                                               const float* __restrict__ rWb,
                                               const float* __restrict__ x,
                                               float* __restrict__ out) {
    int p  = blockIdx.x * 256 + threadIdx.x;
    int f  = blockIdx.y;
    int c0 = blockIdx.z * 32;
    f32x2 acc_y[16], acc_r[16];
#pragma unroll
    for (int cc = 0; cc < 16; ++cc) { acc_y[cc] = 0.f; acc_r[cc] = 0.f; }
#pragma unroll 4
    for (int i8 = 0; i8 < 8; ++i8) {
        size_t base = (((size_t)f * 8 + i8) * P_ + p) * 8;
        u16x8 sy = *(const u16x8*)(Ys + base);
        u16x8 rv = *(const u16x8*)(Yr + base);
#pragma unroll
        for (int j = 0; j < 8; ++j) {
            float ys = b2f(sy[j]);
            float yv = b2f(rv[j]);
            f32x2 ys2; ys2[0] = ys; ys2[1] = ys;
            f32x2 yv2; yv2[0] = yv; yv2[1] = yv;
            int i = i8 * 8 + j;
            const f32x2* wr = (const f32x2*)(WT  + (size_t)i * C_ + c0);
            const f32x2* rw = (const f32x2*)(rWT + (size_t)i * C_ + c0);
#pragma unroll
            for (int cc = 0; cc < 16; ++cc) {
                acc_y[cc] += ys2 * wr[cc];   // v_pk_fma_f32
                acc_r[cc] += yv2 * rw[cc];
            }
        }
    }
#pragma unroll
    for (int cc = 0; cc < 16; ++cc) {
#pragma unroll
        for (int h = 0; h < 2; ++h) {
            int c = c0 + 2 * cc + h;
            size_t o = ((size_t)f * C_ + c) * P_ + p;
            out[o] = acc_y[cc][h] + acc_r[cc][h] + x[o] + Wb[c] + rWb[c];
        }
    }
}

extern "C" void kernel_launch(void* const* d_in, const int* in_sizes, int n_in,
                              void* d_out, int out_size, void* d_ws, size_t ws_size,
                              hipStream_t stream) {
    const float* x    = (const float*)d_in[0];
    const float* rgb  = (const float*)d_in[1];
    const float* g_w  = (const float*)d_in[2];
    const float* g_b  = (const float*)d_in[3];
    const float* th_w = (const float*)d_in[4];
    const float* th_b = (const float*)d_in[5];
    const float* ph_w = (const float*)d_in[6];
    const float* ph_b = (const float*)d_in[7];
    const float* W_w  = (const float*)d_in[8];
    const float* W_b  = (const float*)d_in[9];
    const float* rg_w = (const float*)d_in[10];
    const float* rg_b = (const float*)d_in[11];
    const float* rt_w = (const float*)d_in[12];
    const float* rt_b = (const float*)d_in[13];
    const float* rp_w = (const float*)d_in[14];
    const float* rp_b = (const float*)d_in[15];
    const float* rW_w = (const float*)d_in[16];
    const float* rW_b = (const float*)d_in[17];
    const float* cp_w = (const float*)d_in[18];
    float* out = (float*)d_out;

    const size_t FIP = (size_t)F_ * I_ * P_;   // 4718592
    const size_t SKP = (size_t)F_ * KK_ * P_;  // 10027008

    u16* Gb  = (u16*)d_ws;            // fp16 pairs [f][i2][p][2]
    u16* THb = Gb  + FIP;             // fp16 pairs
    u16* PHb = THb + FIP;             // fp16 pairs
    u16* Sb  = PHb + FIP;             // bf16 [k][p][f1]
    u16* Yp  = Sb  + SKP;             // bf16 [4][f][ib][p][8]
    u16* Yr  = Yp  + 4 * FIP;         // bf16 [f][ib][p][8]
    float* GR  = (float*)(Yr + FIP);  // [i][p] fp32
    float* SR  = GR + (size_t)I_ * P_;
    float* Bf  = SR + P_;
    float* DEN = Bf + (size_t)F_ * P_;        // [4][f][p]
    float* VT  = DEN + 4 * (size_t)F_ * P_;
    float* U   = VT + C_;
    float* CT  = U + C_;
    unsigned* UH   = (unsigned*)(CT + 16);
    float* rgT = (float*)(UH + C2_);
    float* WT  = rgT + (size_t)C_ * I_;
    float* rWT = WT  + (size_t)C_ * I_;
    float* BALL = rWT + (size_t)C_ * I_;       // 256 floats
    _Float16* WPK = (_Float16*)(BALL + 256);   // 26624 halfs
    u16* Ysum = Gb;                   // alias: G dead after k_y
    _Float16* XHT = (_Float16*)Yp;    // alias: xhT dead before k_y writes Yp

    // weight prep
    k_prep<<<1, 128, 0, stream>>>(rt_w, rp_w, rt_b, rp_b, cp_w, VT, U, CT, UH);
    k_tr<<<dim3(32, 3), 256, 0, stream>>>(rg_w, W_w, rW_w, rgT, WT, rWT);
    k_wpk<<<104, 256, 0, stream>>>(g_w, th_w, ph_w, g_b, th_b, ph_b, U, CT, WPK, BALL);

    // x -> fp16 row-major xhT[f][p][c] (aliases Yp region)
    k_xhT<<<dim3(P_ / 256, 4, F_), 256, 0, stream>>>(x, XHT);

    // MFMA projections -> fp16 i-pair packed (G, TH, PH) + Bf (n=192 row)
    k_projm<<<dim3(P_ / 64, 1, F_), 256, 0, stream>>>(XHT, (const h16x8*)WPK, BALL,
                                                      (unsigned*)Gb, (unsigned*)THb,
                                                      (unsigned*)PHb, Bf);

    // rgb-side: GR conv + SR field
    k_rg<<<dim3(P_ / 256, 5), 256, 0, stream>>>(rgb, rgT, rg_b, VT, CT, GR, SR);

    // attention scores via dot2 (k-block 2, 9792 waves)
    k_scores<<<dim3(P_ / 256, KK_ / 2), 256, 0, stream>>>((const unsigned*)PHb,
                                                          (const unsigned*)THb, Sb);

    // attention apply (pk-FMA), f2 quarters x f1 halves -> 9216 waves
    k_y<<<dim3(P_ / 256, I_ / 8, 8), 256, 0, stream>>>(Sb, Gb, Yp, DEN);

    // rgb-branch tap-sum over i (pk-FMA) -> Yr
    k_yr<<<dim3(P_ / 128, I_ / 8), 128, 0, stream>>>(SR, Bf, GR, Yr);

    // fold quarters + softmax denominator -> Ysum (aliases dead G buffer)
    k_fold<<<dim3(P_ / 256, 8, F_), 256, 0, stream>>>(Yp, DEN, Ysum);

    // final: two packed-FMA convs, biases + residual
    k_final<<<dim3(P_ / 256, F_, C_ / 32), 256, 0, stream>>>(Ysum, Yr, WT, rWT,
                                                             W_b, rW_b, x, out);
}

// Round 21
// 178.552 us; speedup vs baseline: 1.1601x; 1.1601x over previous
//
#include <hip/hip_runtime.h>

#define F_ 8
#define C_ 128
#define C2_ (C_/2)   // 64 c-pairs
#define H_ 96
#define W_ 96
#define P_ (H_*W_)   // 9216
#define I_ 64
#define I2_ (I_/2)   // 32 i-pairs
#define T_ 17
#define KK_ (F_*T_)  // 136

// compile-time tap offsets (full unroll -> immediates) — used by k_scores / k_yr
__device__ constexpr int DY[T_] = {-1,-1,-1, 0,0,0, 1,1,1, -3,-3,-3, 0,0, 3,3,3};
__device__ constexpr int DX[T_] = {-1, 0, 1,-1,0,1,-1,0,1, -3, 0, 3,-3,3,-3,0,3};

// dy-grouped tap order for k_y (consecutive taps share cache lines; CK = original k)
__constant__ int CDY[T_] = {-3,-3,-3, -1,-1,-1,  0, 0,0,0, 0,  1,1,1,  3, 3, 3};
__constant__ int CDX[T_] = {-3, 0, 3, -1, 0, 1, -3,-1,0,1, 3, -1,0,1, -3, 0, 3};
__constant__ int CK [T_] = { 9,10,11,  0, 1, 2, 12, 3,4,5,13,  6,7,8, 14,15,16};

typedef unsigned short u16;
typedef u16 u16x8 __attribute__((ext_vector_type(8)));
typedef short s16x8 __attribute__((ext_vector_type(8)));
typedef float f32x2 __attribute__((ext_vector_type(2)));
typedef float f32x4 __attribute__((ext_vector_type(4)));
typedef _Float16 h16x2 __attribute__((ext_vector_type(2)));
typedef _Float16 h16x8 __attribute__((ext_vector_type(8)));

__device__ __forceinline__ float b2f(u16 u) { return __uint_as_float(((unsigned)u) << 16); }
__device__ __forceinline__ u16 f2b(float f) {
    unsigned u = __float_as_uint(f);
    u += 0x7fff + ((u >> 16) & 1);   // RNE
    return (u16)(u >> 16);
}
__device__ __forceinline__ h16x2 u2h(unsigned u) {
    union { unsigned u; h16x2 h; } x; x.u = u; return x.h;
}
__device__ __forceinline__ unsigned packh(float a, float b) {
    union { unsigned u; h16x2 h; } x;
    x.h[0] = (_Float16)a; x.h[1] = (_Float16)b; return x.u;
}
__device__ __forceinline__ float dot2(h16x2 a, h16x2 b, float c) {
#if __has_builtin(__builtin_amdgcn_fdot2)
    return __builtin_amdgcn_fdot2(a, b, c, false);
#else
    return c + (float)a[0] * (float)b[0] + (float)a[1] * (float)b[1];
#endif
}

// vt[c], u[c] fp32; uh = fp16-pair-packed u; ct[0]=wt.rtb; ct[1]=wp.rpb
__global__ __launch_bounds__(128) void k_prep(const float* __restrict__ rtw,
                                              const float* __restrict__ rpw,
                                              const float* __restrict__ rtb,
                                              const float* __restrict__ rpb,
                                              const float* __restrict__ cp,
                                              float* __restrict__ vt,
                                              float* __restrict__ u,
                                              float* __restrict__ ct,
                                              unsigned* __restrict__ uh) {
    __shared__ float su[C_];
    int c = threadIdx.x;  // 128
    float a = 0.f, b2 = 0.f;
    for (int i = 0; i < I_; ++i) {
        a  += cp[i]      * rtw[i*C_ + c];
        b2 += cp[I_ + i] * rpw[i*C_ + c];
    }
    vt[c] = a; u[c] = b2; su[c] = b2;
    if (c == 0) { float s = 0.f; for (int i = 0; i < I_; ++i) s += cp[i]      * rtb[i]; ct[0] = s; }
    if (c == 1) { float s = 0.f; for (int i = 0; i < I_; ++i) s += cp[I_ + i] * rpb[i]; ct[1] = s; }
    __syncthreads();
    if (c < C2_) uh[c] = packh(su[2*c], su[2*c+1]);
}

// rg weight transpose: rgT[c][i] = rg_w[i][c]
__global__ __launch_bounds__(256) void k_tr(const float* __restrict__ rg_w,
                                            float* __restrict__ rgT) {
    int idx = blockIdx.x * 256 + threadIdx.x;   // 8192
    int r = idx / C_, c = idx % C_;
    rgT[c*I_ + r] = rg_w[idx];
}

// MFMA weight prepack (projections): Wpk fragment-linear (13 nt x 4 ks x 64 lanes x 8).
// n<192: proj weights; n==192: u[c] (Bf row); bias table ball[208].
__global__ __launch_bounds__(256) void k_wpk(const float* __restrict__ g_w,
                                             const float* __restrict__ th_w,
                                             const float* __restrict__ ph_w,
                                             const float* __restrict__ g_b,
                                             const float* __restrict__ th_b,
                                             const float* __restrict__ ph_b,
                                             const float* __restrict__ u,
                                             const float* __restrict__ ct,
                                             _Float16* __restrict__ Wpk,
                                             float* __restrict__ ball) {
    int idx = blockIdx.x * 256 + threadIdx.x;   // over 13*4*64*8 = 26624
    if (idx < 26624) {
        int j    = idx & 7;
        int frag = idx >> 3;
        int l    = frag & 63;
        int t    = frag >> 6;      // nt*4 + ks
        int ks   = t & 3;
        int nt   = t >> 2;
        int c = ks * 32 + ((l >> 4) << 3) + j;
        int n = nt * 16 + (l & 15);
        float v;
        if (n < 192) {
            int proj = n >> 6, i = n & 63;
            const float* src = proj == 0 ? g_w : (proj == 1 ? th_w : ph_w);
            v = src[i * C_ + c];
        } else if (n == 192) v = u[c];
        else v = 0.f;
        Wpk[idx] = (_Float16)v;
    }
    if (idx < 208) {
        float b;
        if (idx < 192) {
            int proj = idx >> 6, i = idx & 63;
            const float* bs = proj == 0 ? g_b : (proj == 1 ? th_b : ph_b);
            b = bs[i];
        } else if (idx == 192) b = ct[1];
        else b = 0.f;
        ball[idx] = b;
    }
}

// MFMA weight prepack (final conv): Wpk2 bf16 fragment-linear (8 nt x 4 ks x 64 x 8).
// K=128: k<64 -> W_w[c][k] (Ysum path); k>=64 -> rW_w[c][k-64] (Yr path).
// ball2[c] = Wb[c] + rWb[c].
__global__ __launch_bounds__(256) void k_wpk2(const float* __restrict__ W_w,
                                              const float* __restrict__ rW_w,
                                              const float* __restrict__ Wb,
                                              const float* __restrict__ rWb,
                                              u16* __restrict__ Wpk2,
                                              float* __restrict__ ball2) {
    int idx = blockIdx.x * 256 + threadIdx.x;   // over 8*4*64*8 = 16384
    if (idx < 16384) {
        int j    = idx & 7;
        int frag = idx >> 3;
        int l    = frag & 63;
        int t    = frag >> 6;      // nt*4 + ks
        int ks   = t & 3;
        int nt   = t >> 2;
        int k = ks * 32 + ((l >> 4) << 3) + j;   // i' 0..127
        int n = nt * 16 + (l & 15);              // c 0..127
        float v = (k < 64) ? W_w[n * I_ + k] : rW_w[n * I_ + (k - 64)];
        Wpk2[idx] = f2b(v);
    }
    if (idx < C_) ball2[idx] = Wb[idx] + rWb[idx];
}

// x fp32 [f][c][p] -> fp16 row-major xhT[f][p][c] (c contiguous, MFMA-fragment friendly)
__global__ __launch_bounds__(256) void k_xhT(const float* __restrict__ x,
                                             _Float16* __restrict__ xhT) {
    int p  = blockIdx.x * 256 + threadIdx.x;
    int cb = blockIdx.y;        // 4 blocks of 32 c
    int f  = blockIdx.z;
    const float* xp = x + ((size_t)f * C_ + cb * 32) * P_ + p;
    unsigned r[16];
#pragma unroll
    for (int jj = 0; jj < 16; ++jj) {
        float a = xp[(size_t)(2 * jj)     * P_];
        float b = xp[(size_t)(2 * jj + 1) * P_];
        r[jj] = packh(a, b);
    }
    unsigned* dst = (unsigned*)(xhT + ((size_t)f * P_ + p) * C_ + cb * 32);
#pragma unroll
    for (int q4 = 0; q4 < 4; ++q4) {
        uint4 v; v.x = r[q4*4]; v.y = r[q4*4+1]; v.z = r[q4*4+2]; v.w = r[q4*4+3];
        *(uint4*)(dst + q4 * 4) = v;
    }
}

// MFMA projections: per f, D[n=0..207][px] = W^T x. 16x16x32 f16, fp32 accum.
__global__ __launch_bounds__(256) void k_projm(const _Float16* __restrict__ xhT,
                                               const h16x8* __restrict__ Wpk,
                                               const float* __restrict__ ball,
                                               unsigned* __restrict__ oG,
                                               unsigned* __restrict__ oT,
                                               unsigned* __restrict__ oP,
                                               float* __restrict__ Bf) {
    int wid  = threadIdx.x >> 6;
    int lane = threadIdx.x & 63;
    int px0  = blockIdx.x * 64 + wid * 16;
    int f    = blockIdx.z;
    int lm   = lane & 15;
    int lg   = lane >> 4;
    const _Float16* xrow = xhT + ((size_t)f * P_ + px0 + lm) * C_ + lg * 8;
    h16x8 bfrag[4];
#pragma unroll
    for (int ks = 0; ks < 4; ++ks)
        bfrag[ks] = *(const h16x8*)(xrow + ks * 32);
#pragma unroll 1
    for (int nt = 0; nt < 13; ++nt) {
        f32x4 acc = {0.f, 0.f, 0.f, 0.f};
#pragma unroll
        for (int ks = 0; ks < 4; ++ks) {
            h16x8 afrag = Wpk[(nt * 4 + ks) * 64 + lane];
            acc = __builtin_amdgcn_mfma_f32_16x16x32_f16(afrag, bfrag[ks], acc, 0, 0, 0);
        }
        int nb = nt * 16 + lg * 4;     // 4 consecutive n in regs 0..3
        if (nb < 192) {
            int proj = nb >> 6, i = nb & 63, i2 = i >> 1;
            unsigned* o = proj == 0 ? oG : (proj == 1 ? oT : oP);
            size_t base = ((size_t)f * I2_ + i2) * P_ + px0 + lm;
            o[base]      = packh(acc[0] + ball[nb],     acc[1] + ball[nb + 1]);
            o[base + P_] = packh(acc[2] + ball[nb + 2], acc[3] + ball[nb + 3]);
        } else if (nb == 192) {
            Bf[(size_t)f * P_ + px0 + lm] = acc[0] + ball[192];
        }
    }
}

// y<4: GR[i0..i0+16)[p] fp32 = conv(rgb, rgT) + rg_b;  y==4: SR[p] = ct0 + rgb.vt
__global__ __launch_bounds__(256) void k_rg(const float* __restrict__ rgb,
                                            const float* __restrict__ rgT,
                                            const float* __restrict__ rg_b,
                                            const float* __restrict__ vt,
                                            const float* __restrict__ ct,
                                            float* __restrict__ GR,
                                            float* __restrict__ SR) {
    int p = blockIdx.x * 256 + threadIdx.x;
    int y = blockIdx.y;
    if (y == 4) {
        float s = ct[0];
        for (int c = 0; c < C_; ++c) s += rgb[(size_t)c * P_ + p] * vt[c];
        SR[p] = s;
        return;
    }
    int i0 = y * 16;
    float acc[16];
#pragma unroll
    for (int ii = 0; ii < 16; ++ii) acc[ii] = 0.f;
#pragma unroll 2
    for (int c = 0; c < C_; ++c) {
        float xv = rgb[(size_t)c * P_ + p];
        const float* wr = rgT + (size_t)c * I_ + i0;
#pragma unroll
        for (int ii = 0; ii < 16; ++ii) acc[ii] += xv * wr[ii];
    }
#pragma unroll
    for (int ii = 0; ii < 16; ++ii) GR[(size_t)(i0 + ii) * P_ + p] = acc[ii] + rg_b[i0 + ii];
}

// scores: S[k][p][f1] (bf16) = exp(mask * sum_i PH.TH) via v_dot2 over i-pairs
__global__ __launch_bounds__(256) void k_scores(const unsigned* __restrict__ PHu,
                                                const unsigned* __restrict__ THu,
                                                u16* __restrict__ S) {
    int p  = blockIdx.x * 256 + threadIdx.x;
    int k0 = blockIdx.y * 4;
    int px = p % W_, py = p / W_;
    size_t tb[4]; float msk[4];
#pragma unroll
    for (int kk = 0; kk < 4; ++kk) {
        int k  = k0 + kk;
        int f2 = k / T_;
        int t  = k - f2 * T_;
        int dy = DY[t], dx = DX[t];
        bool v = ((unsigned)(py + dy) < H_) && ((unsigned)(px + dx) < W_);
        int q  = p + dy * W_ + dx;
        q = min(max(q, 0), P_ - 1);
        tb[kk]  = (size_t)f2 * I2_ * P_ + q;
        msk[kk] = v ? 1.f : 0.f;
    }
    float acc[8][4];
#pragma unroll
    for (int a = 0; a < 8; ++a)
#pragma unroll
        for (int b = 0; b < 4; ++b) acc[a][b] = 0.f;
#pragma unroll 2
    for (int i2 = 0; i2 < I2_; ++i2) {
        h16x2 ph[8];
#pragma unroll
        for (int f1 = 0; f1 < 8; ++f1)
            ph[f1] = u2h(PHu[((size_t)f1 * I2_ + i2) * P_ + p]);
        h16x2 tv[4];
#pragma unroll
        for (int kk = 0; kk < 4; ++kk)
            tv[kk] = u2h(THu[tb[kk] + (size_t)i2 * P_]);
#pragma unroll
        for (int kk = 0; kk < 4; ++kk)
#pragma unroll
            for (int f1 = 0; f1 < 8; ++f1)
                acc[f1][kk] = dot2(ph[f1], tv[kk], acc[f1][kk]);
    }
    // exp folded (|score| << 88); OOB -> exp(0)=1, matches reference denominator
#pragma unroll
    for (int kk = 0; kk < 4; ++kk) {
        u16x8 r;
#pragma unroll
        for (int f1 = 0; f1 < 8; ++f1) r[f1] = f2b(__expf(acc[f1][kk] * msk[kk]));
        *(u16x8*)(S + ((size_t)(k0 + kk) * P_ + p) * 8) = r;
    }
}

// k_y: partial over quarter of f2 (2 f2 each). thread = 1px x 8f1 x 8i.
// Packed-FMA outer product: acc2[8][4] f32x2, 32 v_pk_fma per tap.
// Yp[qtr][f][ib][p][8i] bf16; den partial by iblk==0.
__global__ __launch_bounds__(256) void k_y(const u16* __restrict__ S,
                                           const u16* __restrict__ G,
                                           u16* __restrict__ Yp,
                                           float* __restrict__ DEN) {
    int p   = blockIdx.x * 256 + threadIdx.x;
    int ib  = blockIdx.y;           // i-block: i = ib*8 + ii
    int qtr = blockIdx.z;
    int px = p % W_, py = p / W_;
    const unsigned* Gu = (const unsigned*)G;
    f32x2 acc2[8][4];
    float den[8];
#pragma unroll
    for (int a = 0; a < 8; ++a) {
        den[a] = 0.f;
#pragma unroll
        for (int b = 0; b < 4; ++b) acc2[a][b] = 0.f;
    }
#pragma unroll 1
    for (int f2 = qtr * 2; f2 < qtr * 2 + 2; ++f2) {
        const unsigned* Gb = Gu + ((size_t)f2 * I2_ + ib * 4) * P_;
#pragma unroll 1
        for (int t = 0; t < T_; ++t) {
            int dy = CDY[t], dx = CDX[t], k = CK[t];
            bool v = ((unsigned)(py + dy) < H_) && ((unsigned)(px + dx) < W_);
            int q  = p + dy * W_ + dx;
            q = min(max(q, 0), P_ - 1);
            float mt = v ? 1.f : 0.f;
            f32x2 mt2; mt2[0] = mt; mt2[1] = mt;
            u16x8 svv = *(const u16x8*)(S + ((size_t)(f2 * T_ + k) * P_ + p) * 8);
            float sv[8];
#pragma unroll
            for (int ff = 0; ff < 8; ++ff) sv[ff] = b2f(svv[ff]);
            f32x2 gv2[4];
#pragma unroll
            for (int jj = 0; jj < 4; ++jj) {
                h16x2 h = u2h(Gb[(size_t)jj * P_ + q]);
                f32x2 g; g[0] = (float)h[0]; g[1] = (float)h[1];
                gv2[jj] = g * mt2;           // v_pk_mul_f32
            }
#pragma unroll
            for (int ff = 0; ff < 8; ++ff) {
                den[ff] += sv[ff];
                f32x2 s2; s2[0] = sv[ff]; s2[1] = sv[ff];
#pragma unroll
                for (int jj = 0; jj < 4; ++jj)
                    acc2[ff][jj] += s2 * gv2[jj];   // v_pk_fma_f32
            }
        }
    }
    if (blockIdx.y == 0) {
#pragma unroll
        for (int ff = 0; ff < 8; ++ff)
            DEN[(size_t)(qtr * F_ + ff) * P_ + p] = den[ff];
    }
    u16* Yh = Yp + (size_t)qtr * F_ * P_ * I_;
#pragma unroll
    for (int ff = 0; ff < 8; ++ff) {
        u16x8 r;
#pragma unroll
        for (int ii = 0; ii < 8; ++ii) r[ii] = f2b(acc2[ff][ii >> 1][ii & 1]);
        *(u16x8*)(Yh + (((size_t)ff * 8 + ib) * P_ + p) * 8) = r;
    }
}

// Yr[f][ib][p][8i] bf16 = sum_t relu(SR[q]+Bf[f][p])/T * GR[i][q]; pk-FMA over ii-pairs
__global__ __launch_bounds__(128) void k_yr(const float* __restrict__ SR,
                                            const float* __restrict__ Bf,
                                            const float* __restrict__ GR,
                                            u16* __restrict__ Yr) {
    int p  = blockIdx.x * 128 + threadIdx.x;
    int ib = blockIdx.y;
    int i0 = ib * 8;
    int px = p % W_, py = p / W_;
    float bfv[8];
#pragma unroll
    for (int f = 0; f < 8; ++f) bfv[f] = Bf[f * P_ + p];
    f32x2 acc2[8][4];
#pragma unroll
    for (int a = 0; a < 8; ++a)
#pragma unroll
        for (int b = 0; b < 4; ++b) acc2[a][b] = 0.f;
#pragma unroll
    for (int t = 0; t < T_; ++t) {
        int dy = DY[t], dx = DX[t];
        bool v = ((unsigned)(py + dy) < H_) && ((unsigned)(px + dx) < W_);
        int q  = p + dy * W_ + dx;
        q = min(max(q, 0), P_ - 1);
        float sr = SR[q];
        f32x2 gr2[4];
#pragma unroll
        for (int jj = 0; jj < 4; ++jj) {
            f32x2 g;
            g[0] = GR[(size_t)(i0 + 2*jj)     * P_ + q];
            g[1] = GR[(size_t)(i0 + 2*jj + 1) * P_ + q];
            gr2[jj] = g;
        }
#pragma unroll
        for (int f = 0; f < 8; ++f) {
            float fv = v ? fmaxf(sr + bfv[f], 0.f) * (1.f / (float)T_) : 0.f;
            f32x2 f2v; f2v[0] = fv; f2v[1] = fv;
#pragma unroll
            for (int jj = 0; jj < 4; ++jj) acc2[f][jj] += f2v * gr2[jj];
        }
    }
#pragma unroll
    for (int f = 0; f < 8; ++f) {
        u16x8 r;
#pragma unroll
        for (int ii = 0; ii < 8; ++ii) r[ii] = f2b(acc2[f][ii >> 1][ii & 1]);
        *(u16x8*)(Yr + (((size_t)f * 8 + ib) * P_ + p) * 8) = r;
    }
}

// k_fold: Ysum[f][i8][p][8] bf16 = (sum_q Ypq) * dv
__global__ __launch_bounds__(256) void k_fold(const u16* __restrict__ Yp,
                                              const float* __restrict__ DEN,
                                              u16* __restrict__ Ys) {
    int p  = blockIdx.x * 256 + threadIdx.x;
    int i8 = blockIdx.y;
    int f  = blockIdx.z;
    float dv = 1.f / (DEN[(size_t)f * P_ + p]
                    + DEN[(size_t)(F_ + f) * P_ + p]
                    + DEN[(size_t)(2 * F_ + f) * P_ + p]
                    + DEN[(size_t)(3 * F_ + f) * P_ + p]);
    const size_t FPI = (size_t)F_ * P_ * I_;
    size_t base = (((size_t)f * 8 + i8) * P_ + p) * 8;
    u16x8 q0 = *(const u16x8*)(Yp + base);
    u16x8 q1 = *(const u16x8*)(Yp + FPI + base);
    u16x8 q2 = *(const u16x8*)(Yp + 2 * FPI + base);
    u16x8 q3 = *(const u16x8*)(Yp + 3 * FPI + base);
    u16x8 r;
#pragma unroll
    for (int j = 0; j < 8; ++j)
        r[j] = f2b((b2f(q0[j]) + b2f(q1[j]) + b2f(q2[j]) + b2f(q3[j])) * dv);
    *(u16x8*)(Ys + base) = r;
}

// MFMA final conv: out[c][p] = sum_{i'=0..127} Ycat[i'][p]*Wcat[i'][c] + ball2[c] + x.
// Ycat = concat(Ysum, Yr) over K; interleaved [f][ib][p][8] = B-fragment-native.
// bf16 MFMA 16x16x32, fp32 accum; D: col=px (lane&15), row = (lane>>4)*4 + reg.
__global__ __launch_bounds__(256) void k_finalm(const u16* __restrict__ Ys,
                                                const u16* __restrict__ Yr,
                                                const s16x8* __restrict__ Wpk2,
                                                const float* __restrict__ ball2,
                                                const float* __restrict__ x,
                                                float* __restrict__ out) {
    int wid  = threadIdx.x >> 6;
    int lane = threadIdx.x & 63;
    int px0  = blockIdx.x * 64 + wid * 16;
    int f    = blockIdx.y;
    int lm   = lane & 15;
    int lg   = lane >> 4;
    s16x8 bfrag[4];
#pragma unroll
    for (int ks = 0; ks < 4; ++ks) {
        int ip = ks * 32 + lg * 8;             // i' base of this lane's 8 k-elems
        const u16* src = (ip < 64) ? Ys : Yr;
        int ib = (ip & 63) >> 3;
        bfrag[ks] = *(const s16x8*)(src + (((size_t)f * 8 + ib) * P_ + px0 + lm) * 8);
    }
#pragma unroll 1
    for (int nt = 0; nt < 8; ++nt) {
        f32x4 acc = {0.f, 0.f, 0.f, 0.f};
#pragma unroll
        for (int ks = 0; ks < 4; ++ks) {
            s16x8 afrag = Wpk2[(nt * 4 + ks) * 64 + lane];
            acc = __builtin_amdgcn_mfma_f32_16x16x32_bf16(afrag, bfrag[ks], acc, 0, 0, 0);
        }
        int nb = nt * 16 + lg * 4;             // 4 consecutive c in regs 0..3
#pragma unroll
        for (int r = 0; r < 4; ++r) {
            int c = nb + r;
            size_t o = ((size_t)f * C_ + c) * P_ + px0 + lm;
            out[o] = acc[r] + ball2[c] + x[o];
        }
    }
}

extern "C" void kernel_launch(void* const* d_in, const int* in_sizes, int n_in,
                              void* d_out, int out_size, void* d_ws, size_t ws_size,
                              hipStream_t stream) {
    const float* x    = (const float*)d_in[0];
    const float* rgb  = (const float*)d_in[1];
    const float* g_w  = (const float*)d_in[2];
    const float* g_b  = (const float*)d_in[3];
    const float* th_w = (const float*)d_in[4];
    const float* th_b = (const float*)d_in[5];
    const float* ph_w = (const float*)d_in[6];
    const float* ph_b = (const float*)d_in[7];
    const float* W_w  = (const float*)d_in[8];
    const float* W_b  = (const float*)d_in[9];
    const float* rg_w = (const float*)d_in[10];
    const float* rg_b = (const float*)d_in[11];
    const float* rt_w = (const float*)d_in[12];
    const float* rt_b = (const float*)d_in[13];
    const float* rp_w = (const float*)d_in[14];
    const float* rp_b = (const float*)d_in[15];
    const float* rW_w = (const float*)d_in[16];
    const float* rW_b = (const float*)d_in[17];
    const float* cp_w = (const float*)d_in[18];
    float* out = (float*)d_out;

    const size_t FIP = (size_t)F_ * I_ * P_;   // 4718592
    const size_t SKP = (size_t)F_ * KK_ * P_;  // 10027008

    u16* Gb  = (u16*)d_ws;            // fp16 pairs [f][i2][p][2]
    u16* THb = Gb  + FIP;             // fp16 pairs
    u16* PHb = THb + FIP;             // fp16 pairs
    u16* Sb  = PHb + FIP;             // bf16 [k][p][f1]
    u16* Yp  = Sb  + SKP;             // bf16 [4][f][ib][p][8]
    u16* Yr  = Yp  + 4 * FIP;         // bf16 [f][ib][p][8]
    float* GR  = (float*)(Yr + FIP);  // [i][p] fp32
    float* SR  = GR + (size_t)I_ * P_;
    float* Bf  = SR + P_;
    float* DEN = Bf + (size_t)F_ * P_;        // [4][f][p]
    float* VT  = DEN + 4 * (size_t)F_ * P_;
    float* U   = VT + C_;
    float* CT  = U + C_;
    unsigned* UH   = (unsigned*)(CT + 16);
    float* rgT = (float*)(UH + C2_);
    float* BALL = rgT + (size_t)C_ * I_;       // 256 floats
    _Float16* WPK = (_Float16*)(BALL + 256);   // 26624 halfs
    u16* WPK2   = (u16*)(WPK + 26624);         // 16384 bf16
    float* BALL2 = (float*)(WPK2 + 16384);     // 128 floats
    u16* Ysum = Gb;                   // alias: G dead after k_y
    _Float16* XHT = (_Float16*)Yp;    // alias: xhT dead before k_y writes Yp

    // weight prep
    k_prep<<<1, 128, 0, stream>>>(rt_w, rp_w, rt_b, rp_b, cp_w, VT, U, CT, UH);
    k_tr<<<32, 256, 0, stream>>>(rg_w, rgT);
    k_wpk<<<104, 256, 0, stream>>>(g_w, th_w, ph_w, g_b, th_b, ph_b, U, CT, WPK, BALL);
    k_wpk2<<<64, 256, 0, stream>>>(W_w, rW_w, W_b, rW_b, WPK2, BALL2);

    // x -> fp16 row-major xhT[f][p][c] (aliases Yp region)
    k_xhT<<<dim3(P_ / 256, 4, F_), 256, 0, stream>>>(x, XHT);

    // MFMA projections -> fp16 i-pair packed (G, TH, PH) + Bf (n=192 row)
    k_projm<<<dim3(P_ / 64, 1, F_), 256, 0, stream>>>(XHT, (const h16x8*)WPK, BALL,
                                                      (unsigned*)Gb, (unsigned*)THb,
                                                      (unsigned*)PHb, Bf);

    // rgb-side: GR conv + SR field
    k_rg<<<dim3(P_ / 256, 5), 256, 0, stream>>>(rgb, rgT, rg_b, VT, CT, GR, SR);

    // attention scores via dot2 (k-block 4; round-19 best shape)
    k_scores<<<dim3(P_ / 256, KK_ / 4), 256, 0, stream>>>((const unsigned*)PHb,
                                                          (const unsigned*)THb, Sb);

    // attention apply (pk-FMA), f2 quarters, 8 f1 per thread (round-19 best shape)
    k_y<<<dim3(P_ / 256, I_ / 8, 4), 256, 0, stream>>>(Sb, Gb, Yp, DEN);

    // rgb-branch tap-sum over i (pk-FMA) -> Yr
    k_yr<<<dim3(P_ / 128, I_ / 8), 128, 0, stream>>>(SR, Bf, GR, Yr);

    // fold quarters + softmax denominator -> Ysum (aliases dead G buffer)
    k_fold<<<dim3(P_ / 256, 8, F_), 256, 0, stream>>>(Yp, DEN, Ysum);

    // MFMA final: K=128 concat(Ysum,Yr) x Wcat + bias + residual
    k_finalm<<<dim3(P_ / 64, F_), 256, 0, stream>>>(Ysum, Yr, (const s16x8*)WPK2,
                                                    BALL2, x, out);
}

// Round 22
// 168.162 us; speedup vs baseline: 1.2318x; 1.0618x over previous
//
#include <hip/hip_runtime.h>

#define F_ 8
#define C_ 128
#define C2_ (C_/2)   // 64 c-pairs
#define H_ 96
#define W_ 96
#define P_ (H_*W_)   // 9216
#define I_ 64
#define I2_ (I_/2)   // 32 i-pairs
#define T_ 17
#define KK_ (F_*T_)  // 136

// compile-time tap offsets (full unroll -> immediates) — used by k_scores / k_yr
__device__ constexpr int DY[T_] = {-1,-1,-1, 0,0,0, 1,1,1, -3,-3,-3, 0,0, 3,3,3};
__device__ constexpr int DX[T_] = {-1, 0, 1,-1,0,1,-1,0,1, -3, 0, 3,-3,3,-3,0,3};

// dy-grouped tap order for k_y (consecutive taps share cache lines; CK = original k)
__constant__ int CDY[T_] = {-3,-3,-3, -1,-1,-1,  0, 0,0,0, 0,  1,1,1,  3, 3, 3};
__constant__ int CDX[T_] = {-3, 0, 3, -1, 0, 1, -3,-1,0,1, 3, -1,0,1, -3, 0, 3};
__constant__ int CK [T_] = { 9,10,11,  0, 1, 2, 12, 3,4,5,13,  6,7,8, 14,15,16};

typedef unsigned short u16;
typedef u16 u16x8 __attribute__((ext_vector_type(8)));
typedef short s16x8 __attribute__((ext_vector_type(8)));
typedef float f32x2 __attribute__((ext_vector_type(2)));
typedef float f32x4 __attribute__((ext_vector_type(4)));
typedef _Float16 h16x2 __attribute__((ext_vector_type(2)));
typedef _Float16 h16x8 __attribute__((ext_vector_type(8)));

__device__ __forceinline__ float b2f(u16 u) { return __uint_as_float(((unsigned)u) << 16); }
__device__ __forceinline__ u16 f2b(float f) {
    unsigned u = __float_as_uint(f);
    u += 0x7fff + ((u >> 16) & 1);   // RNE
    return (u16)(u >> 16);
}
__device__ __forceinline__ h16x2 u2h(unsigned u) {
    union { unsigned u; h16x2 h; } x; x.u = u; return x.h;
}
__device__ __forceinline__ unsigned packh(float a, float b) {
    union { unsigned u; h16x2 h; } x;
    x.h[0] = (_Float16)a; x.h[1] = (_Float16)b; return x.u;
}
__device__ __forceinline__ h16x2 slice2(h16x8 v, int j) {
    h16x2 r; r[0] = v[2*j]; r[1] = v[2*j+1]; return r;
}
__device__ __forceinline__ float dot2(h16x2 a, h16x2 b, float c) {
#if __has_builtin(__builtin_amdgcn_fdot2)
    return __builtin_amdgcn_fdot2(a, b, c, false);
#else
    return c + (float)a[0] * (float)b[0] + (float)a[1] * (float)b[1];
#endif
}

// vt[c], u[c] fp32; uh = fp16-pair-packed u; ct[0]=wt.rtb; ct[1]=wp.rpb
__global__ __launch_bounds__(128) void k_prep(const float* __restrict__ rtw,
                                              const float* __restrict__ rpw,
                                              const float* __restrict__ rtb,
                                              const float* __restrict__ rpb,
                                              const float* __restrict__ cp,
                                              float* __restrict__ vt,
                                              float* __restrict__ u,
                                              float* __restrict__ ct,
                                              unsigned* __restrict__ uh) {
    __shared__ float su[C_];
    int c = threadIdx.x;  // 128
    float a = 0.f, b2 = 0.f;
    for (int i = 0; i < I_; ++i) {
        a  += cp[i]      * rtw[i*C_ + c];
        b2 += cp[I_ + i] * rpw[i*C_ + c];
    }
    vt[c] = a; u[c] = b2; su[c] = b2;
    if (c == 0) { float s = 0.f; for (int i = 0; i < I_; ++i) s += cp[i]      * rtb[i]; ct[0] = s; }
    if (c == 1) { float s = 0.f; for (int i = 0; i < I_; ++i) s += cp[I_ + i] * rpb[i]; ct[1] = s; }
    __syncthreads();
    if (c < C2_) uh[c] = packh(su[2*c], su[2*c+1]);
}

// rg weight transpose: rgT[c][i] = rg_w[i][c]
__global__ __launch_bounds__(256) void k_tr(const float* __restrict__ rg_w,
                                            float* __restrict__ rgT) {
    int idx = blockIdx.x * 256 + threadIdx.x;   // 8192
    int r = idx / C_, c = idx % C_;
    rgT[c*I_ + r] = rg_w[idx];
}

// MFMA weight prepack (projections): Wpk fragment-linear (13 nt x 4 ks x 64 lanes x 8).
// n<192: proj weights; n==192: u[c] (Bf row); bias table ball[208].
__global__ __launch_bounds__(256) void k_wpk(const float* __restrict__ g_w,
                                             const float* __restrict__ th_w,
                                             const float* __restrict__ ph_w,
                                             const float* __restrict__ g_b,
                                             const float* __restrict__ th_b,
                                             const float* __restrict__ ph_b,
                                             const float* __restrict__ u,
                                             const float* __restrict__ ct,
                                             _Float16* __restrict__ Wpk,
                                             float* __restrict__ ball) {
    int idx = blockIdx.x * 256 + threadIdx.x;   // over 13*4*64*8 = 26624
    if (idx < 26624) {
        int j    = idx & 7;
        int frag = idx >> 3;
        int l    = frag & 63;
        int t    = frag >> 6;      // nt*4 + ks
        int ks   = t & 3;
        int nt   = t >> 2;
        int c = ks * 32 + ((l >> 4) << 3) + j;
        int n = nt * 16 + (l & 15);
        float v;
        if (n < 192) {
            int proj = n >> 6, i = n & 63;
            const float* src = proj == 0 ? g_w : (proj == 1 ? th_w : ph_w);
            v = src[i * C_ + c];
        } else if (n == 192) v = u[c];
        else v = 0.f;
        Wpk[idx] = (_Float16)v;
    }
    if (idx < 208) {
        float b;
        if (idx < 192) {
            int proj = idx >> 6, i = idx & 63;
            const float* bs = proj == 0 ? g_b : (proj == 1 ? th_b : ph_b);
            b = bs[i];
        } else if (idx == 192) b = ct[1];
        else b = 0.f;
        ball[idx] = b;
    }
}

// MFMA weight prepack (final conv): Wpk2 bf16 fragment-linear (8 nt x 4 ks x 64 x 8).
// K=128: k<64 -> W_w[c][k] (Ysum path); k>=64 -> rW_w[c][k-64] (Yr path).
// ball2[c] = Wb[c] + rWb[c].
__global__ __launch_bounds__(256) void k_wpk2(const float* __restrict__ W_w,
                                              const float* __restrict__ rW_w,
                                              const float* __restrict__ Wb,
                                              const float* __restrict__ rWb,
                                              u16* __restrict__ Wpk2,
                                              float* __restrict__ ball2) {
    int idx = blockIdx.x * 256 + threadIdx.x;   // over 8*4*64*8 = 16384
    if (idx < 16384) {
        int j    = idx & 7;
        int frag = idx >> 3;
        int l    = frag & 63;
        int t    = frag >> 6;      // nt*4 + ks
        int ks   = t & 3;
        int nt   = t >> 2;
        int k = ks * 32 + ((l >> 4) << 3) + j;   // i' 0..127
        int n = nt * 16 + (l & 15);              // c 0..127
        float v = (k < 64) ? W_w[n * I_ + k] : rW_w[n * I_ + (k - 64)];
        Wpk2[idx] = f2b(v);
    }
    if (idx < C_) ball2[idx] = Wb[idx] + rWb[idx];
}

// x fp32 [f][c][p] -> fp16 row-major xhT[f][p][c] (c contiguous, MFMA-fragment friendly)
__global__ __launch_bounds__(256) void k_xhT(const float* __restrict__ x,
                                             _Float16* __restrict__ xhT) {
    int p  = blockIdx.x * 256 + threadIdx.x;
    int cb = blockIdx.y;        // 4 blocks of 32 c
    int f  = blockIdx.z;
    const float* xp = x + ((size_t)f * C_ + cb * 32) * P_ + p;
    unsigned r[16];
#pragma unroll
    for (int jj = 0; jj < 16; ++jj) {
        float a = xp[(size_t)(2 * jj)     * P_];
        float b = xp[(size_t)(2 * jj + 1) * P_];
        r[jj] = packh(a, b);
    }
    unsigned* dst = (unsigned*)(xhT + ((size_t)f * P_ + p) * C_ + cb * 32);
#pragma unroll
    for (int q4 = 0; q4 < 4; ++q4) {
        uint4 v; v.x = r[q4*4]; v.y = r[q4*4+1]; v.z = r[q4*4+2]; v.w = r[q4*4+3];
        *(uint4*)(dst + q4 * 4) = v;
    }
}

// MFMA projections: per f, D[n=0..207][px] = W^T x. 16x16x32 f16, fp32 accum.
// Outputs interleaved [f][ib][p][8] fp16 (each lane: 4 consecutive i -> one uint2).
__global__ __launch_bounds__(256) void k_projm(const _Float16* __restrict__ xhT,
                                               const h16x8* __restrict__ Wpk,
                                               const float* __restrict__ ball,
                                               u16* __restrict__ oG,
                                               u16* __restrict__ oT,
                                               u16* __restrict__ oP,
                                               float* __restrict__ Bf) {
    int wid  = threadIdx.x >> 6;
    int lane = threadIdx.x & 63;
    int px0  = blockIdx.x * 64 + wid * 16;
    int f    = blockIdx.z;
    int lm   = lane & 15;
    int lg   = lane >> 4;
    const _Float16* xrow = xhT + ((size_t)f * P_ + px0 + lm) * C_ + lg * 8;
    h16x8 bfrag[4];
#pragma unroll
    for (int ks = 0; ks < 4; ++ks)
        bfrag[ks] = *(const h16x8*)(xrow + ks * 32);
#pragma unroll 1
    for (int nt = 0; nt < 13; ++nt) {
        f32x4 acc = {0.f, 0.f, 0.f, 0.f};
#pragma unroll
        for (int ks = 0; ks < 4; ++ks) {
            h16x8 afrag = Wpk[(nt * 4 + ks) * 64 + lane];
            acc = __builtin_amdgcn_mfma_f32_16x16x32_f16(afrag, bfrag[ks], acc, 0, 0, 0);
        }
        int nb = nt * 16 + lg * 4;     // 4 consecutive n in regs 0..3
        if (nb < 192) {
            int proj = nb >> 6, i = nb & 63;
            int ib = i >> 3, i7 = i & 7;   // i7 in {0,4} -> 8B aligned uint2
            u16* o = proj == 0 ? oG : (proj == 1 ? oT : oP);
            size_t base = (((size_t)f * 8 + ib) * P_ + px0 + lm) * 8 + i7;
            uint2 v;
            v.x = packh(acc[0] + ball[nb],     acc[1] + ball[nb + 1]);
            v.y = packh(acc[2] + ball[nb + 2], acc[3] + ball[nb + 3]);
            *(uint2*)(o + base) = v;
        } else if (nb == 192) {
            Bf[(size_t)f * P_ + px0 + lm] = acc[0] + ball[192];
        }
    }
}

// y<4: GR[i0..i0+16)[p] fp32 = conv(rgb, rgT) + rg_b;  y==4: SR[p] = ct0 + rgb.vt
__global__ __launch_bounds__(256) void k_rg(const float* __restrict__ rgb,
                                            const float* __restrict__ rgT,
                                            const float* __restrict__ rg_b,
                                            const float* __restrict__ vt,
                                            const float* __restrict__ ct,
                                            float* __restrict__ GR,
                                            float* __restrict__ SR) {
    int p = blockIdx.x * 256 + threadIdx.x;
    int y = blockIdx.y;
    if (y == 4) {
        float s = ct[0];
        for (int c = 0; c < C_; ++c) s += rgb[(size_t)c * P_ + p] * vt[c];
        SR[p] = s;
        return;
    }
    int i0 = y * 16;
    float acc[16];
#pragma unroll
    for (int ii = 0; ii < 16; ++ii) acc[ii] = 0.f;
#pragma unroll 2
    for (int c = 0; c < C_; ++c) {
        float xv = rgb[(size_t)c * P_ + p];
        const float* wr = rgT + (size_t)c * I_ + i0;
#pragma unroll
        for (int ii = 0; ii < 16; ++ii) acc[ii] += xv * wr[ii];
    }
#pragma unroll
    for (int ii = 0; ii < 16; ++ii) GR[(size_t)(i0 + ii) * P_ + p] = acc[ii] + rg_b[i0 + ii];
}

// scores: S[k][p][f1] (bf16) = exp(mask * sum_i PH.TH)
// interleaved PH/TH: per ib, 8 coalesced PH h16x8 + 4 gathered TH h16x8 -> 32 dot2x4
__global__ __launch_bounds__(256) void k_scores(const u16* __restrict__ PH,
                                                const u16* __restrict__ TH,
                                                u16* __restrict__ S) {
    int p  = blockIdx.x * 256 + threadIdx.x;
    int k0 = blockIdx.y * 4;
    int px = p % W_, py = p / W_;
    int qs[4], f2s[4]; float msk[4];
#pragma unroll
    for (int kk = 0; kk < 4; ++kk) {
        int k  = k0 + kk;
        int f2 = k / T_;
        int t  = k - f2 * T_;
        int dy = DY[t], dx = DX[t];
        bool v = ((unsigned)(py + dy) < H_) && ((unsigned)(px + dx) < W_);
        int q  = p + dy * W_ + dx;
        q = min(max(q, 0), P_ - 1);
        qs[kk] = q; f2s[kk] = f2;
        msk[kk] = v ? 1.f : 0.f;
    }
    float acc[8][4];
#pragma unroll
    for (int a = 0; a < 8; ++a)
#pragma unroll
        for (int b = 0; b < 4; ++b) acc[a][b] = 0.f;
#pragma unroll 1
    for (int ib = 0; ib < 8; ++ib) {
        h16x8 ph8[8];
#pragma unroll
        for (int f1 = 0; f1 < 8; ++f1)
            ph8[f1] = *(const h16x8*)(PH + (((size_t)f1 * 8 + ib) * P_ + p) * 8);
#pragma unroll
        for (int kk = 0; kk < 4; ++kk) {
            h16x8 th8 = *(const h16x8*)(TH + (((size_t)f2s[kk] * 8 + ib) * P_ + qs[kk]) * 8);
            h16x2 t0 = slice2(th8, 0), t1 = slice2(th8, 1),
                  t2 = slice2(th8, 2), t3 = slice2(th8, 3);
#pragma unroll
            for (int f1 = 0; f1 < 8; ++f1) {
                acc[f1][kk] = dot2(slice2(ph8[f1], 0), t0, acc[f1][kk]);
                acc[f1][kk] = dot2(slice2(ph8[f1], 1), t1, acc[f1][kk]);
                acc[f1][kk] = dot2(slice2(ph8[f1], 2), t2, acc[f1][kk]);
                acc[f1][kk] = dot2(slice2(ph8[f1], 3), t3, acc[f1][kk]);
            }
        }
    }
    // exp folded (|score| << 88); OOB -> exp(0)=1, matches reference denominator
#pragma unroll
    for (int kk = 0; kk < 4; ++kk) {
        u16x8 r;
#pragma unroll
        for (int f1 = 0; f1 < 8; ++f1) r[f1] = f2b(__expf(acc[f1][kk] * msk[kk]));
        *(u16x8*)(S + ((size_t)(k0 + kk) * P_ + p) * 8) = r;
    }
}

// k_y: partial over quarter of f2 (2 f2 each). thread = 1px x 8f1 x 8i.
// Interleaved G: ONE h16x8 gather per tap (was 4 uints). 32 pk-FMA per tap.
// Yp[qtr][f][ib][p][8i] bf16; den partial by iblk==0.
__global__ __launch_bounds__(256) void k_y(const u16* __restrict__ S,
                                           const u16* __restrict__ G,
                                           u16* __restrict__ Yp,
                                           float* __restrict__ DEN) {
    int p   = blockIdx.x * 256 + threadIdx.x;
    int ib  = blockIdx.y;           // i-block: i = ib*8 + ii
    int qtr = blockIdx.z;
    int px = p % W_, py = p / W_;
    f32x2 acc2[8][4];
    float den[8];
#pragma unroll
    for (int a = 0; a < 8; ++a) {
        den[a] = 0.f;
#pragma unroll
        for (int b = 0; b < 4; ++b) acc2[a][b] = 0.f;
    }
#pragma unroll 1
    for (int f2 = qtr * 2; f2 < qtr * 2 + 2; ++f2) {
        const u16* Gb = G + (((size_t)f2 * 8 + ib) * P_) * 8;
#pragma unroll 1
        for (int t = 0; t < T_; ++t) {
            int dy = CDY[t], dx = CDX[t], k = CK[t];
            bool v = ((unsigned)(py + dy) < H_) && ((unsigned)(px + dx) < W_);
            int q  = p + dy * W_ + dx;
            q = min(max(q, 0), P_ - 1);
            float mt = v ? 1.f : 0.f;
            f32x2 mt2; mt2[0] = mt; mt2[1] = mt;
            u16x8 svv = *(const u16x8*)(S + ((size_t)(f2 * T_ + k) * P_ + p) * 8);
            float sv[8];
#pragma unroll
            for (int ff = 0; ff < 8; ++ff) sv[ff] = b2f(svv[ff]);
            h16x8 gh = *(const h16x8*)(Gb + (size_t)q * 8);
            f32x2 gv2[4];
#pragma unroll
            for (int jj = 0; jj < 4; ++jj) {
                f32x2 g; g[0] = (float)gh[2*jj]; g[1] = (float)gh[2*jj+1];
                gv2[jj] = g * mt2;           // v_pk_mul_f32
            }
#pragma unroll
            for (int ff = 0; ff < 8; ++ff) {
                den[ff] += sv[ff];
                f32x2 s2; s2[0] = sv[ff]; s2[1] = sv[ff];
#pragma unroll
                for (int jj = 0; jj < 4; ++jj)
                    acc2[ff][jj] += s2 * gv2[jj];   // v_pk_fma_f32
            }
        }
    }
    if (blockIdx.y == 0) {
#pragma unroll
        for (int ff = 0; ff < 8; ++ff)
            DEN[(size_t)(qtr * F_ + ff) * P_ + p] = den[ff];
    }
    u16* Yh = Yp + (size_t)qtr * F_ * P_ * I_;
#pragma unroll
    for (int ff = 0; ff < 8; ++ff) {
        u16x8 r;
#pragma unroll
        for (int ii = 0; ii < 8; ++ii) r[ii] = f2b(acc2[ff][ii >> 1][ii & 1]);
        *(u16x8*)(Yh + (((size_t)ff * 8 + ib) * P_ + p) * 8) = r;
    }
}

// Yr[f][ib][p][8i] bf16 = sum_t relu(SR[q]+Bf[f][p])/T * GR[i][q]; pk-FMA over ii-pairs
__global__ __launch_bounds__(128) void k_yr(const float* __restrict__ SR,
                                            const float* __restrict__ Bf,
                                            const float* __restrict__ GR,
                                            u16* __restrict__ Yr) {
    int p  = blockIdx.x * 128 + threadIdx.x;
    int ib = blockIdx.y;
    int i0 = ib * 8;
    int px = p % W_, py = p / W_;
    float bfv[8];
#pragma unroll
    for (int f = 0; f < 8; ++f) bfv[f] = Bf[f * P_ + p];
    f32x2 acc2[8][4];
#pragma unroll
    for (int a = 0; a < 8; ++a)
#pragma unroll
        for (int b = 0; b < 4; ++b) acc2[a][b] = 0.f;
#pragma unroll
    for (int t = 0; t < T_; ++t) {
        int dy = DY[t], dx = DX[t];
        bool v = ((unsigned)(py + dy) < H_) && ((unsigned)(px + dx) < W_);
        int q  = p + dy * W_ + dx;
        q = min(max(q, 0), P_ - 1);
        float sr = SR[q];
        f32x2 gr2[4];
#pragma unroll
        for (int jj = 0; jj < 4; ++jj) {
            f32x2 g;
            g[0] = GR[(size_t)(i0 + 2*jj)     * P_ + q];
            g[1] = GR[(size_t)(i0 + 2*jj + 1) * P_ + q];
            gr2[jj] = g;
        }
#pragma unroll
        for (int f = 0; f < 8; ++f) {
            float fv = v ? fmaxf(sr + bfv[f], 0.f) * (1.f / (float)T_) : 0.f;
            f32x2 f2v; f2v[0] = fv; f2v[1] = fv;
#pragma unroll
            for (int jj = 0; jj < 4; ++jj) acc2[f][jj] += f2v * gr2[jj];
        }
    }
#pragma unroll
    for (int f = 0; f < 8; ++f) {
        u16x8 r;
#pragma unroll
        for (int ii = 0; ii < 8; ++ii) r[ii] = f2b(acc2[f][ii >> 1][ii & 1]);
        *(u16x8*)(Yr + (((size_t)f * 8 + ib) * P_ + p) * 8) = r;
    }
}

// k_fold: Ysum[f][i8][p][8] bf16 = (sum_q Ypq) * dv
__global__ __launch_bounds__(256) void k_fold(const u16* __restrict__ Yp,
                                              const float* __restrict__ DEN,
                                              u16* __restrict__ Ys) {
    int p  = blockIdx.x * 256 + threadIdx.x;
    int i8 = blockIdx.y;
    int f  = blockIdx.z;
    float dv = 1.f / (DEN[(size_t)f * P_ + p]
                    + DEN[(size_t)(F_ + f) * P_ + p]
                    + DEN[(size_t)(2 * F_ + f) * P_ + p]
                    + DEN[(size_t)(3 * F_ + f) * P_ + p]);
    const size_t FPI = (size_t)F_ * P_ * I_;
    size_t base = (((size_t)f * 8 + i8) * P_ + p) * 8;
    u16x8 q0 = *(const u16x8*)(Yp + base);
    u16x8 q1 = *(const u16x8*)(Yp + FPI + base);
    u16x8 q2 = *(const u16x8*)(Yp + 2 * FPI + base);
    u16x8 q3 = *(const u16x8*)(Yp + 3 * FPI + base);
    u16x8 r;
#pragma unroll
    for (int j = 0; j < 8; ++j)
        r[j] = f2b((b2f(q0[j]) + b2f(q1[j]) + b2f(q2[j]) + b2f(q3[j])) * dv);
    *(u16x8*)(Ys + base) = r;
}

// MFMA final conv: out[c][p] = sum_{i'=0..127} Ycat[i'][p]*Wcat[i'][c] + ball2[c] + x.
__global__ __launch_bounds__(256) void k_finalm(const u16* __restrict__ Ys,
                                                const u16* __restrict__ Yr,
                                                const s16x8* __restrict__ Wpk2,
                                                const float* __restrict__ ball2,
                                                const float* __restrict__ x,
                                                float* __restrict__ out) {
    int wid  = threadIdx.x >> 6;
    int lane = threadIdx.x & 63;
    int px0  = blockIdx.x * 64 + wid * 16;
    int f    = blockIdx.y;
    int lm   = lane & 15;
    int lg   = lane >> 4;
    s16x8 bfrag[4];
#pragma unroll
    for (int ks = 0; ks < 4; ++ks) {
        int ip = ks * 32 + lg * 8;             // i' base of this lane's 8 k-elems
        const u16* src = (ip < 64) ? Ys : Yr;
        int ib = (ip & 63) >> 3;
        bfrag[ks] = *(const s16x8*)(src + (((size_t)f * 8 + ib) * P_ + px0 + lm) * 8);
    }
#pragma unroll 1
    for (int nt = 0; nt < 8; ++nt) {
        f32x4 acc = {0.f, 0.f, 0.f, 0.f};
#pragma unroll
        for (int ks = 0; ks < 4; ++ks) {
            s16x8 afrag = Wpk2[(nt * 4 + ks) * 64 + lane];
            acc = __builtin_amdgcn_mfma_f32_16x16x32_bf16(afrag, bfrag[ks], acc, 0, 0, 0);
        }
        int nb = nt * 16 + lg * 4;             // 4 consecutive c in regs 0..3
#pragma unroll
        for (int r = 0; r < 4; ++r) {
            int c = nb + r;
            size_t o = ((size_t)f * C_ + c) * P_ + px0 + lm;
            out[o] = acc[r] + ball2[c] + x[o];
        }
    }
}

extern "C" void kernel_launch(void* const* d_in, const int* in_sizes, int n_in,
                              void* d_out, int out_size, void* d_ws, size_t ws_size,
                              hipStream_t stream) {
    const float* x    = (const float*)d_in[0];
    const float* rgb  = (const float*)d_in[1];
    const float* g_w  = (const float*)d_in[2];
    const float* g_b  = (const float*)d_in[3];
    const float* th_w = (const float*)d_in[4];
    const float* th_b = (const float*)d_in[5];
    const float* ph_w = (const float*)d_in[6];
    const float* ph_b = (const float*)d_in[7];
    const float* W_w  = (const float*)d_in[8];
    const float* W_b  = (const float*)d_in[9];
    const float* rg_w = (const float*)d_in[10];
    const float* rg_b = (const float*)d_in[11];
    const float* rt_w = (const float*)d_in[12];
    const float* rt_b = (const float*)d_in[13];
    const float* rp_w = (const float*)d_in[14];
    const float* rp_b = (const float*)d_in[15];
    const float* rW_w = (const float*)d_in[16];
    const float* rW_b = (const float*)d_in[17];
    const float* cp_w = (const float*)d_in[18];
    float* out = (float*)d_out;

    const size_t FIP = (size_t)F_ * I_ * P_;   // 4718592
    const size_t SKP = (size_t)F_ * KK_ * P_;  // 10027008

    u16* Gb  = (u16*)d_ws;            // fp16 interleaved [f][ib][p][8]
    u16* THb = Gb  + FIP;             // fp16 interleaved
    u16* PHb = THb + FIP;             // fp16 interleaved
    u16* Sb  = PHb + FIP;             // bf16 [k][p][f1]
    u16* Yp  = Sb  + SKP;             // bf16 [4][f][ib][p][8]
    u16* Yr  = Yp  + 4 * FIP;         // bf16 [f][ib][p][8]
    float* GR  = (float*)(Yr + FIP);  // [i][p] fp32
    float* SR  = GR + (size_t)I_ * P_;
    float* Bf  = SR + P_;
    float* DEN = Bf + (size_t)F_ * P_;        // [4][f][p]
    float* VT  = DEN + 4 * (size_t)F_ * P_;
    float* U   = VT + C_;
    float* CT  = U + C_;
    unsigned* UH   = (unsigned*)(CT + 16);
    float* rgT = (float*)(UH + C2_);
    float* BALL = rgT + (size_t)C_ * I_;       // 256 floats
    _Float16* WPK = (_Float16*)(BALL + 256);   // 26624 halfs
    u16* WPK2   = (u16*)(WPK + 26624);         // 16384 bf16
    float* BALL2 = (float*)(WPK2 + 16384);     // 128 floats
    u16* Ysum = Gb;                   // alias: G dead after k_y (same layout as Yp)
    _Float16* XHT = (_Float16*)Yp;    // alias: xhT dead before k_y writes Yp

    // weight prep
    k_prep<<<1, 128, 0, stream>>>(rt_w, rp_w, rt_b, rp_b, cp_w, VT, U, CT, UH);
    k_tr<<<32, 256, 0, stream>>>(rg_w, rgT);
    k_wpk<<<104, 256, 0, stream>>>(g_w, th_w, ph_w, g_b, th_b, ph_b, U, CT, WPK, BALL);
    k_wpk2<<<64, 256, 0, stream>>>(W_w, rW_w, W_b, rW_b, WPK2, BALL2);

    // x -> fp16 row-major xhT[f][p][c] (aliases Yp region)
    k_xhT<<<dim3(P_ / 256, 4, F_), 256, 0, stream>>>(x, XHT);

    // MFMA projections -> interleaved fp16 (G, TH, PH) + Bf (n=192 row)
    k_projm<<<dim3(P_ / 64, 1, F_), 256, 0, stream>>>(XHT, (const h16x8*)WPK, BALL,
                                                      Gb, THb, PHb, Bf);

    // rgb-side: GR conv + SR field
    k_rg<<<dim3(P_ / 256, 5), 256, 0, stream>>>(rgb, rgT, rg_b, VT, CT, GR, SR);

    // attention scores (interleaved PH/TH: 16B loads)
    k_scores<<<dim3(P_ / 256, KK_ / 4), 256, 0, stream>>>(PHb, THb, Sb);

    // attention apply (pk-FMA, one 16B G gather per tap), f2 quarters
    k_y<<<dim3(P_ / 256, I_ / 8, 4), 256, 0, stream>>>(Sb, Gb, Yp, DEN);

    // rgb-branch tap-sum over i (pk-FMA) -> Yr
    k_yr<<<dim3(P_ / 128, I_ / 8), 128, 0, stream>>>(SR, Bf, GR, Yr);

    // fold quarters + softmax denominator -> Ysum (aliases dead G buffer)
    k_fold<<<dim3(P_ / 256, 8, F_), 256, 0, stream>>>(Yp, DEN, Ysum);

    // MFMA final: K=128 concat(Ysum,Yr) x Wcat + bias + residual
    k_finalm<<<dim3(P_ / 64, F_), 256, 0, stream>>>(Ysum, Yr, (const s16x8*)WPK2,
                                                    BALL2, x, out);
}

// Round 23
// 159.846 us; speedup vs baseline: 1.2959x; 1.0520x over previous
//
#include <hip/hip_runtime.h>

#define F_ 8
#define C_ 128
#define C2_ (C_/2)   // 64 c-pairs
#define H_ 96
#define W_ 96
#define P_ (H_*W_)   // 9216
#define I_ 64
#define I2_ (I_/2)   // 32 i-pairs
#define T_ 17
#define KK_ (F_*T_)  // 136

// compile-time tap offsets (full unroll -> immediates) — used by k_scores / k_yr
__device__ constexpr int DY[T_] = {-1,-1,-1, 0,0,0, 1,1,1, -3,-3,-3, 0,0, 3,3,3};
__device__ constexpr int DX[T_] = {-1, 0, 1,-1,0,1,-1,0,1, -3, 0, 3,-3,3,-3,0,3};

// dy-grouped tap order for k_y (consecutive taps share cache lines; CK = original k)
__constant__ int CDY[T_] = {-3,-3,-3, -1,-1,-1,  0, 0,0,0, 0,  1,1,1,  3, 3, 3};
__constant__ int CDX[T_] = {-3, 0, 3, -1, 0, 1, -3,-1,0,1, 3, -1,0,1, -3, 0, 3};
__constant__ int CK [T_] = { 9,10,11,  0, 1, 2, 12, 3,4,5,13,  6,7,8, 14,15,16};

typedef unsigned short u16;
typedef u16 u16x8 __attribute__((ext_vector_type(8)));
typedef short s16x8 __attribute__((ext_vector_type(8)));
typedef float f32x2 __attribute__((ext_vector_type(2)));
typedef float f32x4 __attribute__((ext_vector_type(4)));
typedef _Float16 h16x2 __attribute__((ext_vector_type(2)));
typedef _Float16 h16x8 __attribute__((ext_vector_type(8)));

__device__ __forceinline__ float b2f(u16 u) { return __uint_as_float(((unsigned)u) << 16); }
__device__ __forceinline__ u16 f2b(float f) {
    unsigned u = __float_as_uint(f);
    u += 0x7fff + ((u >> 16) & 1);   // RNE
    return (u16)(u >> 16);
}
__device__ __forceinline__ h16x2 u2h(unsigned u) {
    union { unsigned u; h16x2 h; } x; x.u = u; return x.h;
}
__device__ __forceinline__ unsigned packh(float a, float b) {
    union { unsigned u; h16x2 h; } x;
    x.h[0] = (_Float16)a; x.h[1] = (_Float16)b; return x.u;
}
__device__ __forceinline__ h16x2 slice2(h16x8 v, int j) {
    h16x2 r; r[0] = v[2*j]; r[1] = v[2*j+1]; return r;
}
__device__ __forceinline__ float dot2(h16x2 a, h16x2 b, float c) {
#if __has_builtin(__builtin_amdgcn_fdot2)
    return __builtin_amdgcn_fdot2(a, b, c, false);
#else
    return c + (float)a[0] * (float)b[0] + (float)a[1] * (float)b[1];
#endif
}

// vt[c], u[c] fp32; uh = fp16-pair-packed u; ct[0]=wt.rtb; ct[1]=wp.rpb
__global__ __launch_bounds__(128) void k_prep(const float* __restrict__ rtw,
                                              const float* __restrict__ rpw,
                                              const float* __restrict__ rtb,
                                              const float* __restrict__ rpb,
                                              const float* __restrict__ cp,
                                              float* __restrict__ vt,
                                              float* __restrict__ u,
                                              float* __restrict__ ct,
                                              unsigned* __restrict__ uh) {
    __shared__ float su[C_];
    int c = threadIdx.x;  // 128
    float a = 0.f, b2 = 0.f;
    for (int i = 0; i < I_; ++i) {
        a  += cp[i]      * rtw[i*C_ + c];
        b2 += cp[I_ + i] * rpw[i*C_ + c];
    }
    vt[c] = a; u[c] = b2; su[c] = b2;
    if (c == 0) { float s = 0.f; for (int i = 0; i < I_; ++i) s += cp[i]      * rtb[i]; ct[0] = s; }
    if (c == 1) { float s = 0.f; for (int i = 0; i < I_; ++i) s += cp[I_ + i] * rpb[i]; ct[1] = s; }
    __syncthreads();
    if (c < C2_) uh[c] = packh(su[2*c], su[2*c+1]);
}

// merged weight prep: blocks [0,104): Wpk+ball; [104,168): Wpk2+ball2; [168,200): rgT
__global__ __launch_bounds__(256) void k_wprep(const float* __restrict__ g_w,
                                               const float* __restrict__ th_w,
                                               const float* __restrict__ ph_w,
                                               const float* __restrict__ g_b,
                                               const float* __restrict__ th_b,
                                               const float* __restrict__ ph_b,
                                               const float* __restrict__ u,
                                               const float* __restrict__ ct,
                                               const float* __restrict__ W_w,
                                               const float* __restrict__ rW_w,
                                               const float* __restrict__ Wb,
                                               const float* __restrict__ rWb,
                                               const float* __restrict__ rg_w,
                                               _Float16* __restrict__ Wpk,
                                               float* __restrict__ ball,
                                               u16* __restrict__ Wpk2,
                                               float* __restrict__ ball2,
                                               float* __restrict__ rgT) {
    int b = blockIdx.x;
    if (b < 104) {
        int idx = b * 256 + threadIdx.x;   // over 13*4*64*8 = 26624
        if (idx < 26624) {
            int j    = idx & 7;
            int frag = idx >> 3;
            int l    = frag & 63;
            int t    = frag >> 6;      // nt*4 + ks
            int ks   = t & 3;
            int nt   = t >> 2;
            int c = ks * 32 + ((l >> 4) << 3) + j;
            int n = nt * 16 + (l & 15);
            float v;
            if (n < 192) {
                int proj = n >> 6, i = n & 63;
                const float* src = proj == 0 ? g_w : (proj == 1 ? th_w : ph_w);
                v = src[i * C_ + c];
            } else if (n == 192) v = u[c];
            else v = 0.f;
            Wpk[idx] = (_Float16)v;
        }
        if (idx < 208) {
            float bb;
            if (idx < 192) {
                int proj = idx >> 6, i = idx & 63;
                const float* bs = proj == 0 ? g_b : (proj == 1 ? th_b : ph_b);
                bb = bs[i];
            } else if (idx == 192) bb = ct[1];
            else bb = 0.f;
            ball[idx] = bb;
        }
    } else if (b < 168) {
        int idx = (b - 104) * 256 + threadIdx.x;   // over 16384
        if (idx < 16384) {
            int j    = idx & 7;
            int frag = idx >> 3;
            int l    = frag & 63;
            int t    = frag >> 6;
            int ks   = t & 3;
            int nt   = t >> 2;
            int k = ks * 32 + ((l >> 4) << 3) + j;   // i' 0..127
            int n = nt * 16 + (l & 15);              // c 0..127
            float v = (k < 64) ? W_w[n * I_ + k] : rW_w[n * I_ + (k - 64)];
            Wpk2[idx] = f2b(v);
        }
        if (idx < C_) ball2[idx] = Wb[idx] + rWb[idx];
    } else {
        int idx = (b - 168) * 256 + threadIdx.x;   // over 8192
        int r = idx / C_, c = idx % C_;
        rgT[c*I_ + r] = rg_w[idx];
    }
}

// x fp32 [f][c][p] -> fp16 row-major xhT[f][p][c] (c contiguous, MFMA-fragment friendly)
__global__ __launch_bounds__(256) void k_xhT(const float* __restrict__ x,
                                             _Float16* __restrict__ xhT) {
    int p  = blockIdx.x * 256 + threadIdx.x;
    int cb = blockIdx.y;        // 4 blocks of 32 c
    int f  = blockIdx.z;
    const float* xp = x + ((size_t)f * C_ + cb * 32) * P_ + p;
    unsigned r[16];
#pragma unroll
    for (int jj = 0; jj < 16; ++jj) {
        float a = xp[(size_t)(2 * jj)     * P_];
        float b = xp[(size_t)(2 * jj + 1) * P_];
        r[jj] = packh(a, b);
    }
    unsigned* dst = (unsigned*)(xhT + ((size_t)f * P_ + p) * C_ + cb * 32);
#pragma unroll
    for (int q4 = 0; q4 < 4; ++q4) {
        uint4 v; v.x = r[q4*4]; v.y = r[q4*4+1]; v.z = r[q4*4+2]; v.w = r[q4*4+3];
        *(uint4*)(dst + q4 * 4) = v;
    }
}

// MFMA projections: per f, D[n=0..207][px] = W^T x. 16x16x32 f16, fp32 accum.
// Outputs interleaved [f][ib][p][8] fp16 (each lane: 4 consecutive i -> one uint2).
__global__ __launch_bounds__(256) void k_projm(const _Float16* __restrict__ xhT,
                                               const h16x8* __restrict__ Wpk,
                                               const float* __restrict__ ball,
                                               u16* __restrict__ oG,
                                               u16* __restrict__ oT,
                                               u16* __restrict__ oP,
                                               float* __restrict__ Bf) {
    int wid  = threadIdx.x >> 6;
    int lane = threadIdx.x & 63;
    int px0  = blockIdx.x * 64 + wid * 16;
    int f    = blockIdx.z;
    int lm   = lane & 15;
    int lg   = lane >> 4;
    const _Float16* xrow = xhT + ((size_t)f * P_ + px0 + lm) * C_ + lg * 8;
    h16x8 bfrag[4];
#pragma unroll
    for (int ks = 0; ks < 4; ++ks)
        bfrag[ks] = *(const h16x8*)(xrow + ks * 32);
#pragma unroll 1
    for (int nt = 0; nt < 13; ++nt) {
        f32x4 acc = {0.f, 0.f, 0.f, 0.f};
#pragma unroll
        for (int ks = 0; ks < 4; ++ks) {
            h16x8 afrag = Wpk[(nt * 4 + ks) * 64 + lane];
            acc = __builtin_amdgcn_mfma_f32_16x16x32_f16(afrag, bfrag[ks], acc, 0, 0, 0);
        }
        int nb = nt * 16 + lg * 4;     // 4 consecutive n in regs 0..3
        if (nb < 192) {
            int proj = nb >> 6, i = nb & 63;
            int ib = i >> 3, i7 = i & 7;   // i7 in {0,4} -> 8B aligned uint2
            u16* o = proj == 0 ? oG : (proj == 1 ? oT : oP);
            size_t base = (((size_t)f * 8 + ib) * P_ + px0 + lm) * 8 + i7;
            uint2 v;
            v.x = packh(acc[0] + ball[nb],     acc[1] + ball[nb + 1]);
            v.y = packh(acc[2] + ball[nb + 2], acc[3] + ball[nb + 3]);
            *(uint2*)(o + base) = v;
        } else if (nb == 192) {
            Bf[(size_t)f * P_ + px0 + lm] = acc[0] + ball[192];
        }
    }
}

// y<4: GR[i0..i0+16)[p] fp32 = conv(rgb, rgT) + rg_b;  y==4: SR[p] = ct0 + rgb.vt
__global__ __launch_bounds__(256) void k_rg(const float* __restrict__ rgb,
                                            const float* __restrict__ rgT,
                                            const float* __restrict__ rg_b,
                                            const float* __restrict__ vt,
                                            const float* __restrict__ ct,
                                            float* __restrict__ GR,
                                            float* __restrict__ SR) {
    int p = blockIdx.x * 256 + threadIdx.x;
    int y = blockIdx.y;
    if (y == 4) {
        float s = ct[0];
        for (int c = 0; c < C_; ++c) s += rgb[(size_t)c * P_ + p] * vt[c];
        SR[p] = s;
        return;
    }
    int i0 = y * 16;
    float acc[16];
#pragma unroll
    for (int ii = 0; ii < 16; ++ii) acc[ii] = 0.f;
#pragma unroll 2
    for (int c = 0; c < C_; ++c) {
        float xv = rgb[(size_t)c * P_ + p];
        const float* wr = rgT + (size_t)c * I_ + i0;
#pragma unroll
        for (int ii = 0; ii < 16; ++ii) acc[ii] += xv * wr[ii];
    }
#pragma unroll
    for (int ii = 0; ii < 16; ++ii) GR[(size_t)(i0 + ii) * P_ + p] = acc[ii] + rg_b[i0 + ii];
}

// scores: S[k][p][f1] (bf16) = exp(mask * sum_i PH.TH)
// interleaved PH/TH: per ib, 8 coalesced PH h16x8 + 4 gathered TH h16x8 -> 32 dot2x4
__global__ __launch_bounds__(256) void k_scores(const u16* __restrict__ PH,
                                                const u16* __restrict__ TH,
                                                u16* __restrict__ S) {
    int p  = blockIdx.x * 256 + threadIdx.x;
    int k0 = blockIdx.y * 4;
    int px = p % W_, py = p / W_;
    int qs[4], f2s[4]; float msk[4];
#pragma unroll
    for (int kk = 0; kk < 4; ++kk) {
        int k  = k0 + kk;
        int f2 = k / T_;
        int t  = k - f2 * T_;
        int dy = DY[t], dx = DX[t];
        bool v = ((unsigned)(py + dy) < H_) && ((unsigned)(px + dx) < W_);
        int q  = p + dy * W_ + dx;
        q = min(max(q, 0), P_ - 1);
        qs[kk] = q; f2s[kk] = f2;
        msk[kk] = v ? 1.f : 0.f;
    }
    float acc[8][4];
#pragma unroll
    for (int a = 0; a < 8; ++a)
#pragma unroll
        for (int b = 0; b < 4; ++b) acc[a][b] = 0.f;
#pragma unroll 1
    for (int ib = 0; ib < 8; ++ib) {
        h16x8 ph8[8];
#pragma unroll
        for (int f1 = 0; f1 < 8; ++f1)
            ph8[f1] = *(const h16x8*)(PH + (((size_t)f1 * 8 + ib) * P_ + p) * 8);
#pragma unroll
        for (int kk = 0; kk < 4; ++kk) {
            h16x8 th8 = *(const h16x8*)(TH + (((size_t)f2s[kk] * 8 + ib) * P_ + qs[kk]) * 8);
            h16x2 t0 = slice2(th8, 0), t1 = slice2(th8, 1),
                  t2 = slice2(th8, 2), t3 = slice2(th8, 3);
#pragma unroll
            for (int f1 = 0; f1 < 8; ++f1) {
                acc[f1][kk] = dot2(slice2(ph8[f1], 0), t0, acc[f1][kk]);
                acc[f1][kk] = dot2(slice2(ph8[f1], 1), t1, acc[f1][kk]);
                acc[f1][kk] = dot2(slice2(ph8[f1], 2), t2, acc[f1][kk]);
                acc[f1][kk] = dot2(slice2(ph8[f1], 3), t3, acc[f1][kk]);
            }
        }
    }
    // exp folded (|score| << 88); OOB -> exp(0)=1, matches reference denominator
#pragma unroll
    for (int kk = 0; kk < 4; ++kk) {
        u16x8 r;
#pragma unroll
        for (int f1 = 0; f1 < 8; ++f1) r[f1] = f2b(__expf(acc[f1][kk] * msk[kk]));
        *(u16x8*)(S + ((size_t)(k0 + kk) * P_ + p) * 8) = r;
    }
}

// k_y: partial over quarter of f2 (2 f2 each). thread = 1px x 8f1 x 8i.
// Interleaved G: ONE h16x8 gather per tap. 32 pk-FMA per tap.
// Yp[qtr][f][ib][p][8i] bf16; den partial by iblk==0.
__global__ __launch_bounds__(256) void k_y(const u16* __restrict__ S,
                                           const u16* __restrict__ G,
                                           u16* __restrict__ Yp,
                                           float* __restrict__ DEN) {
    int p   = blockIdx.x * 256 + threadIdx.x;
    int ib  = blockIdx.y;           // i-block: i = ib*8 + ii
    int qtr = blockIdx.z;
    int px = p % W_, py = p / W_;
    f32x2 acc2[8][4];
    float den[8];
#pragma unroll
    for (int a = 0; a < 8; ++a) {
        den[a] = 0.f;
#pragma unroll
        for (int b = 0; b < 4; ++b) acc2[a][b] = 0.f;
    }
#pragma unroll 1
    for (int f2 = qtr * 2; f2 < qtr * 2 + 2; ++f2) {
        const u16* Gb = G + (((size_t)f2 * 8 + ib) * P_) * 8;
#pragma unroll 1
        for (int t = 0; t < T_; ++t) {
            int dy = CDY[t], dx = CDX[t], k = CK[t];
            bool v = ((unsigned)(py + dy) < H_) && ((unsigned)(px + dx) < W_);
            int q  = p + dy * W_ + dx;
            q = min(max(q, 0), P_ - 1);
            float mt = v ? 1.f : 0.f;
            f32x2 mt2; mt2[0] = mt; mt2[1] = mt;
            u16x8 svv = *(const u16x8*)(S + ((size_t)(f2 * T_ + k) * P_ + p) * 8);
            float sv[8];
#pragma unroll
            for (int ff = 0; ff < 8; ++ff) sv[ff] = b2f(svv[ff]);
            h16x8 gh = *(const h16x8*)(Gb + (size_t)q * 8);
            f32x2 gv2[4];
#pragma unroll
            for (int jj = 0; jj < 4; ++jj) {
                f32x2 g; g[0] = (float)gh[2*jj]; g[1] = (float)gh[2*jj+1];
                gv2[jj] = g * mt2;           // v_pk_mul_f32
            }
#pragma unroll
            for (int ff = 0; ff < 8; ++ff) {
                den[ff] += sv[ff];
                f32x2 s2; s2[0] = sv[ff]; s2[1] = sv[ff];
#pragma unroll
                for (int jj = 0; jj < 4; ++jj)
                    acc2[ff][jj] += s2 * gv2[jj];   // v_pk_fma_f32
            }
        }
    }
    if (blockIdx.y == 0) {
#pragma unroll
        for (int ff = 0; ff < 8; ++ff)
            DEN[(size_t)(qtr * F_ + ff) * P_ + p] = den[ff];
    }
    u16* Yh = Yp + (size_t)qtr * F_ * P_ * I_;
#pragma unroll
    for (int ff = 0; ff < 8; ++ff) {
        u16x8 r;
#pragma unroll
        for (int ii = 0; ii < 8; ++ii) r[ii] = f2b(acc2[ff][ii >> 1][ii & 1]);
        *(u16x8*)(Yh + (((size_t)ff * 8 + ib) * P_ + p) * 8) = r;
    }
}

// Yr[f][ib][p][8i] bf16 = sum_t relu(SR[q]+Bf[f][p])/T * GR[i][q]; pk-FMA over ii-pairs
__global__ __launch_bounds__(128) void k_yr(const float* __restrict__ SR,
                                            const float* __restrict__ Bf,
                                            const float* __restrict__ GR,
                                            u16* __restrict__ Yr) {
    int p  = blockIdx.x * 128 + threadIdx.x;
    int ib = blockIdx.y;
    int i0 = ib * 8;
    int px = p % W_, py = p / W_;
    float bfv[8];
#pragma unroll
    for (int f = 0; f < 8; ++f) bfv[f] = Bf[f * P_ + p];
    f32x2 acc2[8][4];
#pragma unroll
    for (int a = 0; a < 8; ++a)
#pragma unroll
        for (int b = 0; b < 4; ++b) acc2[a][b] = 0.f;
#pragma unroll
    for (int t = 0; t < T_; ++t) {
        int dy = DY[t], dx = DX[t];
        bool v = ((unsigned)(py + dy) < H_) && ((unsigned)(px + dx) < W_);
        int q  = p + dy * W_ + dx;
        q = min(max(q, 0), P_ - 1);
        float sr = SR[q];
        f32x2 gr2[4];
#pragma unroll
        for (int jj = 0; jj < 4; ++jj) {
            f32x2 g;
            g[0] = GR[(size_t)(i0 + 2*jj)     * P_ + q];
            g[1] = GR[(size_t)(i0 + 2*jj + 1) * P_ + q];
            gr2[jj] = g;
        }
#pragma unroll
        for (int f = 0; f < 8; ++f) {
            float fv = v ? fmaxf(sr + bfv[f], 0.f) * (1.f / (float)T_) : 0.f;
            f32x2 f2v; f2v[0] = fv; f2v[1] = fv;
#pragma unroll
            for (int jj = 0; jj < 4; ++jj) acc2[f][jj] += f2v * gr2[jj];
        }
    }
#pragma unroll
    for (int f = 0; f < 8; ++f) {
        u16x8 r;
#pragma unroll
        for (int ii = 0; ii < 8; ++ii) r[ii] = f2b(acc2[f][ii >> 1][ii & 1]);
        *(u16x8*)(Yr + (((size_t)f * 8 + ib) * P_ + p) * 8) = r;
    }
}

// MFMA final conv with fused fold: B-fragment for k<64 = bf16((sum_q Ypq)*dv);
// k>=64 = Yr. out[c][p] = MFMA + ball2[c] + x.
__global__ __launch_bounds__(256) void k_finalm(const u16* __restrict__ Yp,
                                                const u16* __restrict__ Yr,
                                                const float* __restrict__ DEN,
                                                const s16x8* __restrict__ Wpk2,
                                                const float* __restrict__ ball2,
                                                const float* __restrict__ x,
                                                float* __restrict__ out) {
    int wid  = threadIdx.x >> 6;
    int lane = threadIdx.x & 63;
    int px0  = blockIdx.x * 64 + wid * 16;
    int f    = blockIdx.y;
    int lm   = lane & 15;
    int lg   = lane >> 4;
    int p    = px0 + lm;
    float dv = 1.f / (DEN[(size_t)f * P_ + p]
                    + DEN[(size_t)(F_ + f) * P_ + p]
                    + DEN[(size_t)(2 * F_ + f) * P_ + p]
                    + DEN[(size_t)(3 * F_ + f) * P_ + p]);
    const size_t FPI = (size_t)F_ * P_ * I_;
    s16x8 bfrag[4];
#pragma unroll
    for (int ks = 0; ks < 4; ++ks) {
        int ip = ks * 32 + lg * 8;             // i' base of this lane's 8 k-elems
        if (ip < 64) {
            int ib = ip >> 3;
            size_t base = (((size_t)f * 8 + ib) * P_ + p) * 8;
            u16x8 q0 = *(const u16x8*)(Yp + base);
            u16x8 q1 = *(const u16x8*)(Yp + FPI + base);
            u16x8 q2 = *(const u16x8*)(Yp + 2 * FPI + base);
            u16x8 q3 = *(const u16x8*)(Yp + 3 * FPI + base);
            s16x8 r;
#pragma unroll
            for (int j = 0; j < 8; ++j)
                r[j] = (short)f2b((b2f(q0[j]) + b2f(q1[j]) + b2f(q2[j]) + b2f(q3[j])) * dv);
            bfrag[ks] = r;
        } else {
            int ib = (ip - 64) >> 3;
            bfrag[ks] = *(const s16x8*)(Yr + (((size_t)f * 8 + ib) * P_ + p) * 8);
        }
    }
#pragma unroll 1
    for (int nt = 0; nt < 8; ++nt) {
        f32x4 acc = {0.f, 0.f, 0.f, 0.f};
#pragma unroll
        for (int ks = 0; ks < 4; ++ks) {
            s16x8 afrag = Wpk2[(nt * 4 + ks) * 64 + lane];
            acc = __builtin_amdgcn_mfma_f32_16x16x32_bf16(afrag, bfrag[ks], acc, 0, 0, 0);
        }
        int nb = nt * 16 + lg * 4;             // 4 consecutive c in regs 0..3
#pragma unroll
        for (int r = 0; r < 4; ++r) {
            int c = nb + r;
            size_t o = ((size_t)f * C_ + c) * P_ + p;
            out[o] = acc[r] + ball2[c] + x[o];
        }
    }
}

extern "C" void kernel_launch(void* const* d_in, const int* in_sizes, int n_in,
                              void* d_out, int out_size, void* d_ws, size_t ws_size,
                              hipStream_t stream) {
    const float* x    = (const float*)d_in[0];
    const float* rgb  = (const float*)d_in[1];
    const float* g_w  = (const float*)d_in[2];
    const float* g_b  = (const float*)d_in[3];
    const float* th_w = (const float*)d_in[4];
    const float* th_b = (const float*)d_in[5];
    const float* ph_w = (const float*)d_in[6];
    const float* ph_b = (const float*)d_in[7];
    const float* W_w  = (const float*)d_in[8];
    const float* W_b  = (const float*)d_in[9];
    const float* rg_w = (const float*)d_in[10];
    const float* rg_b = (const float*)d_in[11];
    const float* rt_w = (const float*)d_in[12];
    const float* rt_b = (const float*)d_in[13];
    const float* rp_w = (const float*)d_in[14];
    const float* rp_b = (const float*)d_in[15];
    const float* rW_w = (const float*)d_in[16];
    const float* rW_b = (const float*)d_in[17];
    const float* cp_w = (const float*)d_in[18];
    float* out = (float*)d_out;

    const size_t FIP = (size_t)F_ * I_ * P_;   // 4718592
    const size_t SKP = (size_t)F_ * KK_ * P_;  // 10027008

    u16* Gb  = (u16*)d_ws;            // fp16 interleaved [f][ib][p][8]
    u16* THb = Gb  + FIP;             // fp16 interleaved
    u16* PHb = THb + FIP;             // fp16 interleaved
    u16* Sb  = PHb + FIP;             // bf16 [k][p][f1]
    u16* Yp  = Sb  + SKP;             // bf16 [4][f][ib][p][8]
    u16* Yr  = Yp  + 4 * FIP;         // bf16 [f][ib][p][8]
    float* GR  = (float*)(Yr + FIP);  // [i][p] fp32
    float* SR  = GR + (size_t)I_ * P_;
    float* Bf  = SR + P_;
    float* DEN = Bf + (size_t)F_ * P_;        // [4][f][p]
    float* VT  = DEN + 4 * (size_t)F_ * P_;
    float* U   = VT + C_;
    float* CT  = U + C_;
    unsigned* UH   = (unsigned*)(CT + 16);
    float* rgT = (float*)(UH + C2_);
    float* BALL = rgT + (size_t)C_ * I_;       // 256 floats
    _Float16* WPK = (_Float16*)(BALL + 256);   // 26624 halfs
    u16* WPK2   = (u16*)(WPK + 26624);         // 16384 bf16
    float* BALL2 = (float*)(WPK2 + 16384);     // 128 floats
    _Float16* XHT = (_Float16*)Yp;    // alias: xhT dead before k_y writes Yp

    // scalar prep (produces U/CT needed by k_wprep)
    k_prep<<<1, 128, 0, stream>>>(rt_w, rp_w, rt_b, rp_b, cp_w, VT, U, CT, UH);

    // merged weight prep: Wpk/ball + Wpk2/ball2 + rgT
    k_wprep<<<200, 256, 0, stream>>>(g_w, th_w, ph_w, g_b, th_b, ph_b, U, CT,
                                     W_w, rW_w, W_b, rW_b, rg_w,
                                     WPK, BALL, WPK2, BALL2, rgT);

    // x -> fp16 row-major xhT[f][p][c] (aliases Yp region)
    k_xhT<<<dim3(P_ / 256, 4, F_), 256, 0, stream>>>(x, XHT);

    // MFMA projections -> interleaved fp16 (G, TH, PH) + Bf (n=192 row)
    k_projm<<<dim3(P_ / 64, 1, F_), 256, 0, stream>>>(XHT, (const h16x8*)WPK, BALL,
                                                      Gb, THb, PHb, Bf);

    // rgb-side: GR conv + SR field
    k_rg<<<dim3(P_ / 256, 5), 256, 0, stream>>>(rgb, rgT, rg_b, VT, CT, GR, SR);

    // attention scores (interleaved PH/TH: 16B loads)
    k_scores<<<dim3(P_ / 256, KK_ / 4), 256, 0, stream>>>(PHb, THb, Sb);

    // attention apply (pk-FMA, one 16B G gather per tap), f2 quarters
    k_y<<<dim3(P_ / 256, I_ / 8, 4), 256, 0, stream>>>(Sb, Gb, Yp, DEN);

    // rgb-branch tap-sum over i (pk-FMA) -> Yr
    k_yr<<<dim3(P_ / 128, I_ / 8), 128, 0, stream>>>(SR, Bf, GR, Yr);

    // MFMA final with fused quarter-fold: K=128 concat(fold(Yp),Yr) x Wcat + bias + residual
    k_finalm<<<dim3(P_ / 64, F_), 256, 0, stream>>>(Yp, Yr, DEN, (const s16x8*)WPK2,
                                                    BALL2, x, out);
}

// Round 24
// 149.672 us; speedup vs baseline: 1.3840x; 1.0680x over previous
//
#include <hip/hip_runtime.h>

#define F_ 8
#define C_ 128
#define C2_ (C_/2)   // 64 c-pairs
#define H_ 96
#define W_ 96
#define P_ (H_*W_)   // 9216
#define I_ 64
#define I2_ (I_/2)   // 32 i-pairs
#define T_ 17
#define KK_ (F_*T_)  // 136

// compile-time tap offsets (full unroll -> immediates) — used by k_scores / yr path
__device__ constexpr int DY[T_] = {-1,-1,-1, 0,0,0, 1,1,1, -3,-3,-3, 0,0, 3,3,3};
__device__ constexpr int DX[T_] = {-1, 0, 1,-1,0,1,-1,0,1, -3, 0, 3,-3,3,-3,0,3};

// dy-grouped tap order for k_y path (consecutive taps share cache lines)
__constant__ int CDY[T_] = {-3,-3,-3, -1,-1,-1,  0, 0,0,0, 0,  1,1,1,  3, 3, 3};
__constant__ int CDX[T_] = {-3, 0, 3, -1, 0, 1, -3,-1,0,1, 3, -1,0,1, -3, 0, 3};
__constant__ int CK [T_] = { 9,10,11,  0, 1, 2, 12, 3,4,5,13,  6,7,8, 14,15,16};

typedef unsigned short u16;
typedef u16 u16x8 __attribute__((ext_vector_type(8)));
typedef short s16x8 __attribute__((ext_vector_type(8)));
typedef float f32x2 __attribute__((ext_vector_type(2)));
typedef float f32x4 __attribute__((ext_vector_type(4)));
typedef _Float16 h16x2 __attribute__((ext_vector_type(2)));
typedef _Float16 h16x8 __attribute__((ext_vector_type(8)));

__device__ __forceinline__ float b2f(u16 u) { return __uint_as_float(((unsigned)u) << 16); }
__device__ __forceinline__ u16 f2b(float f) {
    unsigned u = __float_as_uint(f);
    u += 0x7fff + ((u >> 16) & 1);   // RNE
    return (u16)(u >> 16);
}
__device__ __forceinline__ h16x2 u2h(unsigned u) {
    union { unsigned u; h16x2 h; } x; x.u = u; return x.h;
}
__device__ __forceinline__ unsigned packh(float a, float b) {
    union { unsigned u; h16x2 h; } x;
    x.h[0] = (_Float16)a; x.h[1] = (_Float16)b; return x.u;
}
__device__ __forceinline__ h16x2 slice2(h16x8 v, int j) {
    h16x2 r; r[0] = v[2*j]; r[1] = v[2*j+1]; return r;
}
__device__ __forceinline__ float dot2(h16x2 a, h16x2 b, float c) {
#if __has_builtin(__builtin_amdgcn_fdot2)
    return __builtin_amdgcn_fdot2(a, b, c, false);
#else
    return c + (float)a[0] * (float)b[0] + (float)a[1] * (float)b[1];
#endif
}

// vt[c], u[c] fp32; uh = fp16-pair-packed u; ct[0]=wt.rtb; ct[1]=wp.rpb
__global__ __launch_bounds__(128) void k_prep(const float* __restrict__ rtw,
                                              const float* __restrict__ rpw,
                                              const float* __restrict__ rtb,
                                              const float* __restrict__ rpb,
                                              const float* __restrict__ cp,
                                              float* __restrict__ vt,
                                              float* __restrict__ u,
                                              float* __restrict__ ct,
                                              unsigned* __restrict__ uh) {
    __shared__ float su[C_];
    int c = threadIdx.x;  // 128
    float a = 0.f, b2 = 0.f;
    for (int i = 0; i < I_; ++i) {
        a  += cp[i]      * rtw[i*C_ + c];
        b2 += cp[I_ + i] * rpw[i*C_ + c];
    }
    vt[c] = a; u[c] = b2; su[c] = b2;
    if (c == 0) { float s = 0.f; for (int i = 0; i < I_; ++i) s += cp[i]      * rtb[i]; ct[0] = s; }
    if (c == 1) { float s = 0.f; for (int i = 0; i < I_; ++i) s += cp[I_ + i] * rpb[i]; ct[1] = s; }
    __syncthreads();
    if (c < C2_) uh[c] = packh(su[2*c], su[2*c+1]);
}

// merged weight prep: blocks [0,104): Wpk+ball; [104,168): Wpk2+ball2; [168,200): rgT
__global__ __launch_bounds__(256) void k_wprep(const float* __restrict__ g_w,
                                               const float* __restrict__ th_w,
                                               const float* __restrict__ ph_w,
                                               const float* __restrict__ g_b,
                                               const float* __restrict__ th_b,
                                               const float* __restrict__ ph_b,
                                               const float* __restrict__ u,
                                               const float* __restrict__ ct,
                                               const float* __restrict__ W_w,
                                               const float* __restrict__ rW_w,
                                               const float* __restrict__ Wb,
                                               const float* __restrict__ rWb,
                                               const float* __restrict__ rg_w,
                                               _Float16* __restrict__ Wpk,
                                               float* __restrict__ ball,
                                               u16* __restrict__ Wpk2,
                                               float* __restrict__ ball2,
                                               float* __restrict__ rgT) {
    int b = blockIdx.x;
    if (b < 104) {
        int idx = b * 256 + threadIdx.x;   // over 13*4*64*8 = 26624
        if (idx < 26624) {
            int j    = idx & 7;
            int frag = idx >> 3;
            int l    = frag & 63;
            int t    = frag >> 6;      // nt*4 + ks
            int ks   = t & 3;
            int nt   = t >> 2;
            int c = ks * 32 + ((l >> 4) << 3) + j;
            int n = nt * 16 + (l & 15);
            float v;
            if (n < 192) {
                int proj = n >> 6, i = n & 63;
                const float* src = proj == 0 ? g_w : (proj == 1 ? th_w : ph_w);
                v = src[i * C_ + c];
            } else if (n == 192) v = u[c];
            else v = 0.f;
            Wpk[idx] = (_Float16)v;
        }
        if (idx < 208) {
            float bb;
            if (idx < 192) {
                int proj = idx >> 6, i = idx & 63;
                const float* bs = proj == 0 ? g_b : (proj == 1 ? th_b : ph_b);
                bb = bs[i];
            } else if (idx == 192) bb = ct[1];
            else bb = 0.f;
            ball[idx] = bb;
        }
    } else if (b < 168) {
        int idx = (b - 104) * 256 + threadIdx.x;   // over 16384
        if (idx < 16384) {
            int j    = idx & 7;
            int frag = idx >> 3;
            int l    = frag & 63;
            int t    = frag >> 6;
            int ks   = t & 3;
            int nt   = t >> 2;
            int k = ks * 32 + ((l >> 4) << 3) + j;   // i' 0..127
            int n = nt * 16 + (l & 15);              // c 0..127
            float v = (k < 64) ? W_w[n * I_ + k] : rW_w[n * I_ + (k - 64)];
            Wpk2[idx] = f2b(v);
        }
        if (idx < C_) ball2[idx] = Wb[idx] + rWb[idx];
    } else {
        int idx = (b - 168) * 256 + threadIdx.x;   // over 8192
        int r = idx / C_, c = idx % C_;
        rgT[c*I_ + r] = rg_w[idx];
    }
}

// MERGED: y<32 -> x->fp16 xhT[f][p][c]; y>=32 -> rg conv (GR) / SR field
__global__ __launch_bounds__(256) void k_xr(const float* __restrict__ x,
                                            const float* __restrict__ rgb,
                                            const float* __restrict__ rgT,
                                            const float* __restrict__ rg_b,
                                            const float* __restrict__ vt,
                                            const float* __restrict__ ct,
                                            _Float16* __restrict__ xhT,
                                            float* __restrict__ GR,
                                            float* __restrict__ SR) {
    int yb = blockIdx.y;
    int p  = blockIdx.x * 256 + threadIdx.x;
    if (yb < 32) {
        int cb = yb & 3;          // 4 blocks of 32 c
        int f  = yb >> 2;
        const float* xp = x + ((size_t)f * C_ + cb * 32) * P_ + p;
        unsigned r[16];
#pragma unroll
        for (int jj = 0; jj < 16; ++jj) {
            float a = xp[(size_t)(2 * jj)     * P_];
            float b = xp[(size_t)(2 * jj + 1) * P_];
            r[jj] = packh(a, b);
        }
        unsigned* dst = (unsigned*)(xhT + ((size_t)f * P_ + p) * C_ + cb * 32);
#pragma unroll
        for (int q4 = 0; q4 < 4; ++q4) {
            uint4 v; v.x = r[q4*4]; v.y = r[q4*4+1]; v.z = r[q4*4+2]; v.w = r[q4*4+3];
            *(uint4*)(dst + q4 * 4) = v;
        }
        return;
    }
    int y = yb - 32;              // 0..4
    if (y == 4) {
        float s = ct[0];
        for (int c = 0; c < C_; ++c) s += rgb[(size_t)c * P_ + p] * vt[c];
        SR[p] = s;
        return;
    }
    int i0 = y * 16;
    float acc[16];
#pragma unroll
    for (int ii = 0; ii < 16; ++ii) acc[ii] = 0.f;
#pragma unroll 2
    for (int c = 0; c < C_; ++c) {
        float xv = rgb[(size_t)c * P_ + p];
        const float* wr = rgT + (size_t)c * I_ + i0;
#pragma unroll
        for (int ii = 0; ii < 16; ++ii) acc[ii] += xv * wr[ii];
    }
#pragma unroll
    for (int ii = 0; ii < 16; ++ii) GR[(size_t)(i0 + ii) * P_ + p] = acc[ii] + rg_b[i0 + ii];
}

// MFMA projections: per f, D[n=0..207][px] = W^T x. 16x16x32 f16, fp32 accum.
// Outputs interleaved [f][ib][p][8] fp16 (each lane: 4 consecutive i -> one uint2).
__global__ __launch_bounds__(256) void k_projm(const _Float16* __restrict__ xhT,
                                               const h16x8* __restrict__ Wpk,
                                               const float* __restrict__ ball,
                                               u16* __restrict__ oG,
                                               u16* __restrict__ oT,
                                               u16* __restrict__ oP,
                                               float* __restrict__ Bf) {
    int wid  = threadIdx.x >> 6;
    int lane = threadIdx.x & 63;
    int px0  = blockIdx.x * 64 + wid * 16;
    int f    = blockIdx.z;
    int lm   = lane & 15;
    int lg   = lane >> 4;
    const _Float16* xrow = xhT + ((size_t)f * P_ + px0 + lm) * C_ + lg * 8;
    h16x8 bfrag[4];
#pragma unroll
    for (int ks = 0; ks < 4; ++ks)
        bfrag[ks] = *(const h16x8*)(xrow + ks * 32);
#pragma unroll 1
    for (int nt = 0; nt < 13; ++nt) {
        f32x4 acc = {0.f, 0.f, 0.f, 0.f};
#pragma unroll
        for (int ks = 0; ks < 4; ++ks) {
            h16x8 afrag = Wpk[(nt * 4 + ks) * 64 + lane];
            acc = __builtin_amdgcn_mfma_f32_16x16x32_f16(afrag, bfrag[ks], acc, 0, 0, 0);
        }
        int nb = nt * 16 + lg * 4;     // 4 consecutive n in regs 0..3
        if (nb < 192) {
            int proj = nb >> 6, i = nb & 63;
            int ib = i >> 3, i7 = i & 7;   // i7 in {0,4} -> 8B aligned uint2
            u16* o = proj == 0 ? oG : (proj == 1 ? oT : oP);
            size_t base = (((size_t)f * 8 + ib) * P_ + px0 + lm) * 8 + i7;
            uint2 v;
            v.x = packh(acc[0] + ball[nb],     acc[1] + ball[nb + 1]);
            v.y = packh(acc[2] + ball[nb + 2], acc[3] + ball[nb + 3]);
            *(uint2*)(o + base) = v;
        } else if (nb == 192) {
            Bf[(size_t)f * P_ + px0 + lm] = acc[0] + ball[192];
        }
    }
}

// scores: S[k][p][f1] (bf16) = exp(mask * sum_i PH.TH)
// interleaved PH/TH: per ib, 8 coalesced PH h16x8 + 4 gathered TH h16x8 -> 32 dot2x4
__global__ __launch_bounds__(256) void k_scores(const u16* __restrict__ PH,
                                                const u16* __restrict__ TH,
                                                u16* __restrict__ S) {
    int p  = blockIdx.x * 256 + threadIdx.x;
    int k0 = blockIdx.y * 4;
    int px = p % W_, py = p / W_;
    int qs[4], f2s[4]; float msk[4];
#pragma unroll
    for (int kk = 0; kk < 4; ++kk) {
        int k  = k0 + kk;
        int f2 = k / T_;
        int t  = k - f2 * T_;
        int dy = DY[t], dx = DX[t];
        bool v = ((unsigned)(py + dy) < H_) && ((unsigned)(px + dx) < W_);
        int q  = p + dy * W_ + dx;
        q = min(max(q, 0), P_ - 1);
        qs[kk] = q; f2s[kk] = f2;
        msk[kk] = v ? 1.f : 0.f;
    }
    float acc[8][4];
#pragma unroll
    for (int a = 0; a < 8; ++a)
#pragma unroll
        for (int b = 0; b < 4; ++b) acc[a][b] = 0.f;
#pragma unroll 1
    for (int ib = 0; ib < 8; ++ib) {
        h16x8 ph8[8];
#pragma unroll
        for (int f1 = 0; f1 < 8; ++f1)
            ph8[f1] = *(const h16x8*)(PH + (((size_t)f1 * 8 + ib) * P_ + p) * 8);
#pragma unroll
        for (int kk = 0; kk < 4; ++kk) {
            h16x8 th8 = *(const h16x8*)(TH + (((size_t)f2s[kk] * 8 + ib) * P_ + qs[kk]) * 8);
            h16x2 t0 = slice2(th8, 0), t1 = slice2(th8, 1),
                  t2 = slice2(th8, 2), t3 = slice2(th8, 3);
#pragma unroll
            for (int f1 = 0; f1 < 8; ++f1) {
                acc[f1][kk] = dot2(slice2(ph8[f1], 0), t0, acc[f1][kk]);
                acc[f1][kk] = dot2(slice2(ph8[f1], 1), t1, acc[f1][kk]);
                acc[f1][kk] = dot2(slice2(ph8[f1], 2), t2, acc[f1][kk]);
                acc[f1][kk] = dot2(slice2(ph8[f1], 3), t3, acc[f1][kk]);
            }
        }
    }
    // exp folded (|score| << 88); OOB -> exp(0)=1, matches reference denominator
#pragma unroll
    for (int kk = 0; kk < 4; ++kk) {
        u16x8 r;
#pragma unroll
        for (int f1 = 0; f1 < 8; ++f1) r[f1] = f2b(__expf(acc[f1][kk] * msk[kk]));
        *(u16x8*)(S + ((size_t)(k0 + kk) * P_ + p) * 8) = r;
    }
}

// MERGED attention apply: z<4 -> k_y quarter (Yp partial + den); z==4 -> k_yr.
__global__ __launch_bounds__(256) void k_attn(const u16* __restrict__ S,
                                              const u16* __restrict__ G,
                                              const float* __restrict__ SR,
                                              const float* __restrict__ Bf,
                                              const float* __restrict__ GR,
                                              u16* __restrict__ Yp,
                                              float* __restrict__ DEN,
                                              u16* __restrict__ Yr) {
    int p  = blockIdx.x * 256 + threadIdx.x;
    int ib = blockIdx.y;           // i-block: i = ib*8 + ii
    int z  = blockIdx.z;
    int px = p % W_, py = p / W_;
    if (z < 4) {
        int qtr = z;
        f32x2 acc2[8][4];
        float den[8];
#pragma unroll
        for (int a = 0; a < 8; ++a) {
            den[a] = 0.f;
#pragma unroll
            for (int b = 0; b < 4; ++b) acc2[a][b] = 0.f;
        }
#pragma unroll 1
        for (int f2 = qtr * 2; f2 < qtr * 2 + 2; ++f2) {
            const u16* Gb = G + (((size_t)f2 * 8 + ib) * P_) * 8;
#pragma unroll 1
            for (int t = 0; t < T_; ++t) {
                int dy = CDY[t], dx = CDX[t], k = CK[t];
                bool v = ((unsigned)(py + dy) < H_) && ((unsigned)(px + dx) < W_);
                int q  = p + dy * W_ + dx;
                q = min(max(q, 0), P_ - 1);
                float mt = v ? 1.f : 0.f;
                f32x2 mt2; mt2[0] = mt; mt2[1] = mt;
                u16x8 svv = *(const u16x8*)(S + ((size_t)(f2 * T_ + k) * P_ + p) * 8);
                float sv[8];
#pragma unroll
                for (int ff = 0; ff < 8; ++ff) sv[ff] = b2f(svv[ff]);
                h16x8 gh = *(const h16x8*)(Gb + (size_t)q * 8);
                f32x2 gv2[4];
#pragma unroll
                for (int jj = 0; jj < 4; ++jj) {
                    f32x2 g; g[0] = (float)gh[2*jj]; g[1] = (float)gh[2*jj+1];
                    gv2[jj] = g * mt2;           // v_pk_mul_f32
                }
#pragma unroll
                for (int ff = 0; ff < 8; ++ff) {
                    den[ff] += sv[ff];
                    f32x2 s2; s2[0] = sv[ff]; s2[1] = sv[ff];
#pragma unroll
                    for (int jj = 0; jj < 4; ++jj)
                        acc2[ff][jj] += s2 * gv2[jj];   // v_pk_fma_f32
                }
            }
        }
        if (ib == 0) {
#pragma unroll
            for (int ff = 0; ff < 8; ++ff)
                DEN[(size_t)(qtr * F_ + ff) * P_ + p] = den[ff];
        }
        u16* Yh = Yp + (size_t)qtr * F_ * P_ * I_;
#pragma unroll
        for (int ff = 0; ff < 8; ++ff) {
            u16x8 r;
#pragma unroll
            for (int ii = 0; ii < 8; ++ii) r[ii] = f2b(acc2[ff][ii >> 1][ii & 1]);
            *(u16x8*)(Yh + (((size_t)ff * 8 + ib) * P_ + p) * 8) = r;
        }
        return;
    }
    // z == 4: Yr path
    int i0 = ib * 8;
    float bfv[8];
#pragma unroll
    for (int f = 0; f < 8; ++f) bfv[f] = Bf[f * P_ + p];
    f32x2 acc2[8][4];
#pragma unroll
    for (int a = 0; a < 8; ++a)
#pragma unroll
        for (int b = 0; b < 4; ++b) acc2[a][b] = 0.f;
#pragma unroll
    for (int t = 0; t < T_; ++t) {
        int dy = DY[t], dx = DX[t];
        bool v = ((unsigned)(py + dy) < H_) && ((unsigned)(px + dx) < W_);
        int q  = p + dy * W_ + dx;
        q = min(max(q, 0), P_ - 1);
        float sr = SR[q];
        f32x2 gr2[4];
#pragma unroll
        for (int jj = 0; jj < 4; ++jj) {
            f32x2 g;
            g[0] = GR[(size_t)(i0 + 2*jj)     * P_ + q];
            g[1] = GR[(size_t)(i0 + 2*jj + 1) * P_ + q];
            gr2[jj] = g;
        }
#pragma unroll
        for (int f = 0; f < 8; ++f) {
            float fv = v ? fmaxf(sr + bfv[f], 0.f) * (1.f / (float)T_) : 0.f;
            f32x2 f2v; f2v[0] = fv; f2v[1] = fv;
#pragma unroll
            for (int jj = 0; jj < 4; ++jj) acc2[f][jj] += f2v * gr2[jj];
        }
    }
#pragma unroll
    for (int f = 0; f < 8; ++f) {
        u16x8 r;
#pragma unroll
        for (int ii = 0; ii < 8; ++ii) r[ii] = f2b(acc2[f][ii >> 1][ii & 1]);
        *(u16x8*)(Yr + (((size_t)f * 8 + ib) * P_ + p) * 8) = r;
    }
}

// MFMA final conv with fused fold: B-fragment for k<64 = bf16((sum_q Ypq)*dv);
// k>=64 = Yr. out[c][p] = MFMA + ball2[c] + x.
__global__ __launch_bounds__(256) void k_finalm(const u16* __restrict__ Yp,
                                                const u16* __restrict__ Yr,
                                                const float* __restrict__ DEN,
                                                const s16x8* __restrict__ Wpk2,
                                                const float* __restrict__ ball2,
                                                const float* __restrict__ x,
                                                float* __restrict__ out) {
    int wid  = threadIdx.x >> 6;
    int lane = threadIdx.x & 63;
    int px0  = blockIdx.x * 64 + wid * 16;
    int f    = blockIdx.y;
    int lm   = lane & 15;
    int lg   = lane >> 4;
    int p    = px0 + lm;
    float dv = 1.f / (DEN[(size_t)f * P_ + p]
                    + DEN[(size_t)(F_ + f) * P_ + p]
                    + DEN[(size_t)(2 * F_ + f) * P_ + p]
                    + DEN[(size_t)(3 * F_ + f) * P_ + p]);
    const size_t FPI = (size_t)F_ * P_ * I_;
    s16x8 bfrag[4];
#pragma unroll
    for (int ks = 0; ks < 4; ++ks) {
        int ip = ks * 32 + lg * 8;             // i' base of this lane's 8 k-elems
        if (ip < 64) {
            int ib = ip >> 3;
            size_t base = (((size_t)f * 8 + ib) * P_ + p) * 8;
            u16x8 q0 = *(const u16x8*)(Yp + base);
            u16x8 q1 = *(const u16x8*)(Yp + FPI + base);
            u16x8 q2 = *(const u16x8*)(Yp + 2 * FPI + base);
            u16x8 q3 = *(const u16x8*)(Yp + 3 * FPI + base);
            s16x8 r;
#pragma unroll
            for (int j = 0; j < 8; ++j)
                r[j] = (short)f2b((b2f(q0[j]) + b2f(q1[j]) + b2f(q2[j]) + b2f(q3[j])) * dv);
            bfrag[ks] = r;
        } else {
            int ib = (ip - 64) >> 3;
            bfrag[ks] = *(const s16x8*)(Yr + (((size_t)f * 8 + ib) * P_ + p) * 8);
        }
    }
#pragma unroll 1
    for (int nt = 0; nt < 8; ++nt) {
        f32x4 acc = {0.f, 0.f, 0.f, 0.f};
#pragma unroll
        for (int ks = 0; ks < 4; ++ks) {
            s16x8 afrag = Wpk2[(nt * 4 + ks) * 64 + lane];
            acc = __builtin_amdgcn_mfma_f32_16x16x32_bf16(afrag, bfrag[ks], acc, 0, 0, 0);
        }
        int nb = nt * 16 + lg * 4;             // 4 consecutive c in regs 0..3
#pragma unroll
        for (int r = 0; r < 4; ++r) {
            int c = nb + r;
            size_t o = ((size_t)f * C_ + c) * P_ + p;
            out[o] = acc[r] + ball2[c] + x[o];
        }
    }
}

extern "C" void kernel_launch(void* const* d_in, const int* in_sizes, int n_in,
                              void* d_out, int out_size, void* d_ws, size_t ws_size,
                              hipStream_t stream) {
    const float* x    = (const float*)d_in[0];
    const float* rgb  = (const float*)d_in[1];
    const float* g_w  = (const float*)d_in[2];
    const float* g_b  = (const float*)d_in[3];
    const float* th_w = (const float*)d_in[4];
    const float* th_b = (const float*)d_in[5];
    const float* ph_w = (const float*)d_in[6];
    const float* ph_b = (const float*)d_in[7];
    const float* W_w  = (const float*)d_in[8];
    const float* W_b  = (const float*)d_in[9];
    const float* rg_w = (const float*)d_in[10];
    const float* rg_b = (const float*)d_in[11];
    const float* rt_w = (const float*)d_in[12];
    const float* rt_b = (const float*)d_in[13];
    const float* rp_w = (const float*)d_in[14];
    const float* rp_b = (const float*)d_in[15];
    const float* rW_w = (const float*)d_in[16];
    const float* rW_b = (const float*)d_in[17];
    const float* cp_w = (const float*)d_in[18];
    float* out = (float*)d_out;

    const size_t FIP = (size_t)F_ * I_ * P_;   // 4718592
    const size_t SKP = (size_t)F_ * KK_ * P_;  // 10027008

    u16* Gb  = (u16*)d_ws;            // fp16 interleaved [f][ib][p][8]
    u16* THb = Gb  + FIP;             // fp16 interleaved
    u16* PHb = THb + FIP;             // fp16 interleaved
    u16* Sb  = PHb + FIP;             // bf16 [k][p][f1]
    u16* Yp  = Sb  + SKP;             // bf16 [4][f][ib][p][8]
    u16* Yr  = Yp  + 4 * FIP;         // bf16 [f][ib][p][8]
    float* GR  = (float*)(Yr + FIP);  // [i][p] fp32
    float* SR  = GR + (size_t)I_ * P_;
    float* Bf  = SR + P_;
    float* DEN = Bf + (size_t)F_ * P_;        // [4][f][p]
    float* VT  = DEN + 4 * (size_t)F_ * P_;
    float* U   = VT + C_;
    float* CT  = U + C_;
    unsigned* UH   = (unsigned*)(CT + 16);
    float* rgT = (float*)(UH + C2_);
    float* BALL = rgT + (size_t)C_ * I_;       // 256 floats
    _Float16* WPK = (_Float16*)(BALL + 256);   // 26624 halfs
    u16* WPK2   = (u16*)(WPK + 26624);         // 16384 bf16
    float* BALL2 = (float*)(WPK2 + 16384);     // 128 floats
    _Float16* XHT = (_Float16*)Yp;    // alias: xhT dead before k_attn writes Yp

    // scalar prep (produces U/CT needed by k_wprep)
    k_prep<<<1, 128, 0, stream>>>(rt_w, rp_w, rt_b, rp_b, cp_w, VT, U, CT, UH);

    // merged weight prep: Wpk/ball + Wpk2/ball2 + rgT
    k_wprep<<<200, 256, 0, stream>>>(g_w, th_w, ph_w, g_b, th_b, ph_b, U, CT,
                                     W_w, rW_w, W_b, rW_b, rg_w,
                                     WPK, BALL, WPK2, BALL2, rgT);

    // merged: x -> fp16 xhT (y<32) + rgb-side GR/SR (y>=32)
    k_xr<<<dim3(P_ / 256, 37), 256, 0, stream>>>(x, rgb, rgT, rg_b, VT, CT,
                                                 XHT, GR, SR);

    // MFMA projections -> interleaved fp16 (G, TH, PH) + Bf (n=192 row)
    k_projm<<<dim3(P_ / 64, 1, F_), 256, 0, stream>>>(XHT, (const h16x8*)WPK, BALL,
                                                      Gb, THb, PHb, Bf);

    // attention scores (interleaved PH/TH: 16B loads)
    k_scores<<<dim3(P_ / 256, KK_ / 4), 256, 0, stream>>>(PHb, THb, Sb);

    // merged attention apply: z<4 -> Yp quarters + den; z==4 -> Yr
    k_attn<<<dim3(P_ / 256, I_ / 8, 5), 256, 0, stream>>>(Sb, Gb, SR, Bf, GR,
                                                          Yp, DEN, Yr);

    // MFMA final with fused quarter-fold: K=128 concat(fold(Yp),Yr) x Wcat + bias + residual
    k_finalm<<<dim3(P_ / 64, F_), 256, 0, stream>>>(Yp, Yr, DEN, (const s16x8*)WPK2,
                                                    BALL2, x, out);
}